// Round 16
// baseline (448.104 us; speedup 1.0000x reference)
//
#include <hip/hip_runtime.h>

#define NN 16384
#define CC 512
#define EE 524288
#define BB 64
#define HH 8
#define EFD 16
#define GEMAXE 10240

typedef __bf16 bf16_t;
typedef __bf16 bf16x4 __attribute__((ext_vector_type(4)));
typedef __bf16 bf16x8 __attribute__((ext_vector_type(8)));
typedef float f32x4v __attribute__((ext_vector_type(4)));

__device__ __forceinline__ float2 ldb2(const bf16_t* p) {
  unsigned w = *(const unsigned*)p;
  return make_float2(__uint_as_float(w << 16), __uint_as_float(w & 0xFFFF0000u));
}

// XCD-aware chunked swizzle (nwg % 8 == 0 for all our grids)
__device__ __forceinline__ int2 xcd_swizzle() {
  int nwg = gridDim.x * gridDim.y;
  int bid = blockIdx.y * gridDim.x + blockIdx.x;
  int wg = (bid & 7) * (nwg >> 3) + (bid >> 3);
  return make_int2(wg % gridDim.x, wg / gridDim.x);
}

// ---------------- init / edge pre-pass ----------------

__global__ void init_kernel(int* ghist, int* nid_src, bf16_t* eacsr) {
  int i = threadIdx.x;
  if (i < 64) ghist[i] = 0;
  if (i < 32) nid_src[EE + i] = -1;               // pad for ef chunk tail
  ((int*)(eacsr + (size_t)EE * 16))[i] = 0;       // zero eacsr pad rows (256 ints)
}

// per-graph histogram only (LDS-aggregated)
__global__ __launch_bounds__(256) void edge_pass1(const int* __restrict__ dst,
                                                  int* ghist) {
  __shared__ int h[64];
  int tid = threadIdx.x;
  if (tid < 64) h[tid] = 0;
  __syncthreads();
  int e = blockIdx.x * 256 + tid;  // EE % 256 == 0
  atomicAdd(&h[dst[e] >> 8], 1);
  __syncthreads();
  if (tid < 64 && h[tid]) atomicAdd(&ghist[tid], h[tid]);
}

__global__ void gexscan_kernel(const int* __restrict__ ghist, int* __restrict__ gstart,
                               int* __restrict__ gcur) {
  if (threadIdx.x == 0) {
    int s = 0;
    for (int g = 0; g < 64; ++g) { gstart[g] = s; gcur[g] = s; s += ghist[g]; }
    gstart[64] = s;
  }
}

// bucket edges by graph with block-aggregated offsets; emit packed records.
// ew computed inline from ea (single pass over edge_attr).
__global__ __launch_bounds__(256) void graph_scatter_kernel(
    const int* __restrict__ src, const int* __restrict__ dst,
    const float* __restrict__ ea, int* gcur, int2* __restrict__ grec,
    float* __restrict__ ewg) {
  __shared__ int h[64], base[64], h2[64];
  int tid = threadIdx.x;
  if (tid < 64) { h[tid] = 0; h2[tid] = 0; }
  __syncthreads();
  int e0 = blockIdx.x * 2048;
  int gloc[8];
#pragma unroll
  for (int k = 0; k < 8; ++k) {
    gloc[k] = dst[e0 + k * 256 + tid] >> 8;
    atomicAdd(&h[gloc[k]], 1);
  }
  __syncthreads();
  if (tid < 64) base[tid] = h[tid] ? atomicAdd(&gcur[tid], h[tid]) : 0;
  __syncthreads();
#pragma unroll
  for (int k = 0; k < 8; ++k) {
    int e = e0 + k * 256 + tid;
    int g = gloc[k];
    int p = atomicAdd(&h2[g], 1);
    int pos = base[g] + p;
    int ls = src[e] & 255;
    int ld = dst[e] & 255;
    grec[pos] = make_int2(e | (ls << 19), ld);
    const float4* pa = (const float4*)(ea + (size_t)e * EFD);
    float s = 0.f;
#pragma unroll
    for (int q = 0; q < 4; ++q) {
      float4 v = pa[q];
      s += v.x * v.x + v.y * v.y + v.z * v.z + v.w * v.w;
    }
    ewg[pos] = sqrtf(s);
  }
}

// per-graph LDS counting sort, 128 blocks: blockIdx<64 -> DST pass, else SRC.
__global__ __launch_bounds__(1024) void graph_sort2_kernel(
    const int2* __restrict__ grec, const float* __restrict__ ewg,
    const int* __restrict__ gstart, int* __restrict__ elist_src,
    int* __restrict__ nid_src, int* __restrict__ start_src,
    float2* __restrict__ dstrec, int* __restrict__ start_dst,
    float* __restrict__ dinv) {
  __shared__ int lbuf[GEMAXE];
  __shared__ unsigned short sl[GEMAXE];
  __shared__ float ewl[GEMAXE];
  __shared__ int h[256], hx[256], h2[256];
  __shared__ float fdinv[256];
  const int g = blockIdx.x & 63;
  const int tid = threadIdx.x;
  const int gs = gstart[g];
  const int cnt = gstart[g + 1] - gs;
  if (tid < 256) { h[tid] = 0; h2[tid] = 0; }
  __syncthreads();
  if (blockIdx.x < 64) {
    for (int i = tid; i < cnt; i += 1024) {
      int2 r = grec[gs + i];
      int ld = r.y;
      sl[i] = (unsigned short)(((r.x >> 19) & 255) | (ld << 8));
      ewl[i] = ewg[gs + i];
      atomicAdd(&h[ld], 1);
    }
    __syncthreads();
    int myc = (tid < 256) ? h[tid] : 0;
    for (int off = 1; off < 256; off <<= 1) {
      int v = (tid < 256 && tid >= off) ? h[tid - off] : 0;
      __syncthreads();
      if (tid < 256) h[tid] += v;
      __syncthreads();
    }
    if (tid < 256) {
      hx[tid] = h[tid] - myc;
      start_dst[g * 256 + tid] = gs + hx[tid];
    }
    if (g == 63 && tid == 0) start_dst[NN] = EE;
    __syncthreads();
    for (int i = tid; i < cnt; i += 1024) {
      int ld = sl[i] >> 8;
      int p = hx[ld] + atomicAdd(&h2[ld], 1);
      lbuf[p] = i;
    }
    __syncthreads();
    if (tid < 256) {
      float dg = 1.0f;
      int s0 = hx[tid], e0 = s0 + myc;
      for (int i = s0; i < e0; ++i) dg += ewl[lbuf[i]];
      float dv = rsqrtf(fmaxf(dg, 1e-12f));
      fdinv[tid] = dv;
      dinv[g * 256 + tid] = dv;
    }
    __syncthreads();
    for (int p = tid; p < cnt; p += 1024) {
      int i = lbuf[p];
      int ls = sl[i] & 255;
      int ld = sl[i] >> 8;
      dstrec[gs + p] =
          make_float2(fdinv[ls] * ewl[i] * fdinv[ld], __int_as_float(ls));
    }
  } else {
    int* wb = (int*)ewl;
    for (int i = tid; i < cnt; i += 1024) {
      int w = grec[gs + i].x;
      wb[i] = w;
      atomicAdd(&h[w >> 19], 1);
    }
    __syncthreads();
    int myc = (tid < 256) ? h[tid] : 0;
    for (int off = 1; off < 256; off <<= 1) {
      int v = (tid < 256 && tid >= off) ? h[tid - off] : 0;
      __syncthreads();
      if (tid < 256) h[tid] += v;
      __syncthreads();
    }
    if (tid < 256) {
      hx[tid] = h[tid] - myc;
      start_src[g * 256 + tid] = gs + hx[tid];
    }
    if (g == 63 && tid == 0) start_src[NN] = EE;
    __syncthreads();
    for (int i = tid; i < cnt; i += 1024) {
      int w = wb[i];
      int ls = w >> 19;
      int p = hx[ls] + atomicAdd(&h2[ls], 1);
      lbuf[p] = w;
    }
    __syncthreads();
    for (int p = tid; p < cnt; p += 1024) {
      int w = lbuf[p];
      elist_src[gs + p] = w & 0x7FFFF;
      nid_src[gs + p] = g * 256 + (w >> 19);
    }
  }
}

// gather edge_attr rows into CSR order as bf16
__global__ void ea_gather_kernel(const float* __restrict__ ea,
                                 const int* __restrict__ elist,
                                 bf16_t* __restrict__ eacsr) {
  int idx = blockIdx.x * 256 + threadIdx.x;
  if (idx >= EE * 2) return;
  int pos = idx >> 1, half = idx & 1;
  int e = elist[pos];
  const f32x4v* p = (const f32x4v*)(ea + (size_t)e * EFD + half * 8);
  f32x4v u0 = p[0], u1 = p[1];
  bf16x8 f;
#pragma unroll
  for (int r = 0; r < 4; ++r) {
    f[r] = (bf16_t)u0[r];
    f[4 + r] = (bf16_t)u1[r];
  }
  *(bf16x8*)(eacsr + (size_t)pos * 16 + half * 8) = f;
}

// ---------------- dense per-graph adjacency build ----------------
__global__ __launch_bounds__(256) void an_build_kernel(
    const float2* __restrict__ dstrec, const int* __restrict__ start_dst,
    const float* __restrict__ dinv, bf16_t* __restrict__ An) {
  __shared__ float AnS[128][256];  // 128 KB
  const int g = blockIdx.x >> 1, h = blockIdx.x & 1;
  const int tid = threadIdx.x;
  float4* az = (float4*)&AnS[0][0];
  for (int i = tid; i < 128 * 256 / 4; i += 256)
    az[i] = make_float4(0.f, 0.f, 0.f, 0.f);
  __syncthreads();
  const int nbase = g * 256 + h * 128;
  if (tid < 128) {
    int node = nbase + tid;
    int st = start_dst[node], en = start_dst[node + 1];
    float* row = AnS[tid];
    for (int p = st; p < en; ++p) {
      float2 r = dstrec[p];
      row[__float_as_int(r.y)] += r.x;
    }
    float dv = dinv[node];
    row[h * 128 + tid] += dv * dv;
  }
  __syncthreads();
  bf16_t* out = An + (size_t)nbase * 256;
  const float* s0 = &AnS[0][0];
  for (int i = tid; i < 128 * 256 / 8; i += 256) {
    bf16x8 v;
#pragma unroll
    for (int r = 0; r < 8; ++r) v[r] = (bf16_t)s0[i * 8 + r];
    *(bf16x8*)(out + i * 8) = v;
  }
}

// ---------------- conversions ----------------

__global__ void cvt_bf16_kernel(const float* __restrict__ in, bf16_t* __restrict__ out,
                                int n4) {
  int i = blockIdx.x * 256 + threadIdx.x;
  if (i >= n4) return;
  float4 v = ((const float4*)in)[i];
  bf16x4 o;
  o[0] = (bf16_t)v.x; o[1] = (bf16_t)v.y; o[2] = (bf16_t)v.z; o[3] = (bf16_t)v.w;
  ((bf16x4*)out)[i] = o;
}

// W: f32 [K][N] row-major -> Wt: bf16 [N][K] row-major
__global__ __launch_bounds__(256) void wt_kernel(const float* __restrict__ W,
                                                 bf16_t* __restrict__ Wt, int K, int N) {
  __shared__ float tile[32][33];
  int bx = blockIdx.x * 32;
  int by = blockIdx.y * 32;
  int tx = threadIdx.x & 31, ty = threadIdx.x >> 5;
#pragma unroll
  for (int i = 0; i < 32; i += 8)
    tile[ty + i][tx] = W[(size_t)(by + ty + i) * N + bx + tx];
  __syncthreads();
#pragma unroll
  for (int i = 0; i < 32; i += 8)
    Wt[(size_t)(bx + ty + i) * K + by + tx] = (bf16_t)tile[tx][ty + i];
}

// ---------------- edge projection via double-MFMA (8 waves x 64 cols) ------
__global__ __launch_bounds__(512) void ef_mfma_kernel(
    const bf16_t* __restrict__ eacsr, const float* __restrict__ ep_w,
    const float* __restrict__ ep_b, const int* __restrict__ nid,
    const int* __restrict__ start, bf16_t* __restrict__ efb) {
  const int tid = threadIdx.x;
  const int lane = tid & 63;
  const int wv = tid >> 6;      // 0..7
  const int l15 = lane & 15;
  const int g = lane >> 4;
  const int n0 = blockIdx.x * 16;
  const int cbase = wv * 64;

  bf16x8 wfr[4];
#pragma unroll
  for (int t = 0; t < 4; ++t) {
    bf16x8 f = {};
    int c = cbase + t * 16 + l15;
    if (g < 2) {
#pragma unroll
      for (int j = 0; j < 8; ++j) f[j] = (bf16_t)ep_w[(g * 8 + j) * CC + c];
    } else if (g == 2) {
      f[0] = (bf16_t)ep_b[c];
    }
    wfr[t] = f;
  }

  const int st = start[n0];
  const int en = start[n0 + 16];
  const int tgt = n0 + l15;

  f32x4v eacc[4] = {};

  for (int cb = st; cb < en; cb += 32) {
    bf16x8 af[2];
#pragma unroll
    for (int mE = 0; mE < 2; ++mE) {
      bf16x8 f = {};
      if (g < 2) {
        f = *(const bf16x8*)(eacsr + (size_t)(cb + mE * 16 + l15) * 16 + g * 8);
      } else if (g == 2) {
        f[0] = (bf16_t)1.0f;
      }
      af[mE] = f;
    }
    int4 idlo = *(const int4*)(nid + cb + g * 4);
    int4 idhi = *(const int4*)(nid + cb + 16 + g * 4);
    bf16x8 sf;
    sf[0] = (idlo.x == tgt) ? (bf16_t)1.0f : (bf16_t)0.0f;
    sf[1] = (idlo.y == tgt) ? (bf16_t)1.0f : (bf16_t)0.0f;
    sf[2] = (idlo.z == tgt) ? (bf16_t)1.0f : (bf16_t)0.0f;
    sf[3] = (idlo.w == tgt) ? (bf16_t)1.0f : (bf16_t)0.0f;
    sf[4] = (idhi.x == tgt) ? (bf16_t)1.0f : (bf16_t)0.0f;
    sf[5] = (idhi.y == tgt) ? (bf16_t)1.0f : (bf16_t)0.0f;
    sf[6] = (idhi.z == tgt) ? (bf16_t)1.0f : (bf16_t)0.0f;
    sf[7] = (idhi.w == tgt) ? (bf16_t)1.0f : (bf16_t)0.0f;
#pragma unroll
    for (int t = 0; t < 4; ++t) {
      f32x4v s0 = {}, s1 = {};
      s0 = __builtin_amdgcn_mfma_f32_16x16x32_bf16(af[0], wfr[t], s0, 0, 0, 0);
      s1 = __builtin_amdgcn_mfma_f32_16x16x32_bf16(af[1], wfr[t], s1, 0, 0, 0);
      union { bf16x8 v; bf16x4 h[2]; } pf;
#pragma unroll
      for (int r = 0; r < 4; ++r) {
        pf.h[0][r] = (bf16_t)fmaxf(s0[r], 0.f);
        pf.h[1][r] = (bf16_t)fmaxf(s1[r], 0.f);
      }
      eacc[t] = __builtin_amdgcn_mfma_f32_16x16x32_bf16(sf, pf.v, eacc[t], 0, 0, 0);
    }
  }
#pragma unroll
  for (int t = 0; t < 4; ++t) {
    int c = cbase + t * 16 + l15;
#pragma unroll
    for (int r = 0; r < 4; ++r) {
      int node = n0 + g * 4 + r;
      efb[(size_t)node * (2 * CC) + CC + c] = (bf16_t)eacc[t][r];
    }
  }
}

// ---------------- bf16 MFMA GEMM: dbuf 2-phase (stage-first), BK=32 --------
__device__ __forceinline__ void gl_lds16(const bf16_t* g, bf16_t* l) {
  __builtin_amdgcn_global_load_lds(
      (const __attribute__((address_space(1))) void*)g,
      (__attribute__((address_space(3))) void*)l, 16, 0, 0);
}

// LDS [2][128][32] bf16 per matrix (64B rows), content swizzled: LDS slot s of
// row r holds global k-slot s^(r&3). Stage: linear dest, pre-swizzled source.
// Read: slot q at LDS slot q^(r&3) -> 2 lanes per 16B slot (conflict-free).
// Per iter: issue stage(t+1) BEFORE compute(t); ONE barrier per iter (T3 min).
template <int ACT, int OUT>
__global__ __launch_bounds__(256) void gemm_bf16_kernel(
    const bf16_t* __restrict__ A, const bf16_t* __restrict__ Bt,
    const float* __restrict__ bias, void* __restrict__ Cout, int M, int N, int K) {
  __shared__ __align__(16) bf16_t Al[2][128 * 32];
  __shared__ __align__(16) bf16_t Bl[2][128 * 32];
  const int tid = threadIdx.x;
  const int lane = tid & 63;
  const int wave = tid >> 6;
  int2 sw = xcd_swizzle();
  const int row0 = sw.y * 128;
  const int col0 = sw.x * 128;
  const int wm = (wave >> 1) * 64;
  const int wn = (wave & 1) * 64;
  f32x4v acc[4][4] = {};
  // staging: per issue, thread t covers row (t>>2), slot (t&3); swizzled src
  const int srow = tid >> 2;
  const int sslot8 = (((tid & 3) ^ (srow & 3))) * 8;
  const bf16_t* aBase = A + (size_t)(row0 + srow) * K + sslot8;
  const bf16_t* bBase = Bt + (size_t)(col0 + srow) * K + sslot8;
  const int ldsOff = wave * 512;  // 64 lanes x 16B = 512 bf16 per wave
  const int fr = lane & 15;
  const int g = lane >> 4;
  const int f3 = fr & 3;
  const int nt = K >> 5;
  // prologue: stage tile 0 into buf 0
  gl_lds16(aBase, Al[0] + ldsOff);
  gl_lds16(aBase + (size_t)64 * K, Al[0] + 2048 + ldsOff);
  gl_lds16(bBase, Bl[0] + ldsOff);
  gl_lds16(bBase + (size_t)64 * K, Bl[0] + 2048 + ldsOff);
  __syncthreads();
  for (int t = 0; t < nt; ++t) {
    int cur = t & 1;
    if (t + 1 < nt) {
      int k0 = (t + 1) << 5;
      gl_lds16(aBase + k0, Al[cur ^ 1] + ldsOff);
      gl_lds16(aBase + (size_t)64 * K + k0, Al[cur ^ 1] + 2048 + ldsOff);
      gl_lds16(bBase + k0, Bl[cur ^ 1] + ldsOff);
      gl_lds16(bBase + (size_t)64 * K + k0, Bl[cur ^ 1] + 2048 + ldsOff);
    }
    const int sl = (g ^ f3) * 8;
    bf16x8 af[4], bfv[4];
#pragma unroll
    for (int m = 0; m < 4; ++m)
      af[m] = *(const bf16x8*)(Al[cur] + (wm + m * 16 + fr) * 32 + sl);
#pragma unroll
    for (int n = 0; n < 4; ++n)
      bfv[n] = *(const bf16x8*)(Bl[cur] + (wn + n * 16 + fr) * 32 + sl);
#pragma unroll
    for (int m = 0; m < 4; ++m)
#pragma unroll
      for (int n = 0; n < 4; ++n)
        acc[m][n] =
            __builtin_amdgcn_mfma_f32_16x16x32_bf16(af[m], bfv[n], acc[m][n], 0, 0, 0);
    __syncthreads();
  }
  const int fq = (lane >> 4) * 4;
#pragma unroll
  for (int m = 0; m < 4; ++m) {
    int grb = row0 + wm + m * 16 + fq;
#pragma unroll
    for (int n = 0; n < 4; ++n) {
      int gc = col0 + wn + n * 16 + fr;
      float bv = bias ? bias[gc] : 0.f;
#pragma unroll
      for (int r = 0; r < 4; ++r) {
        float v = acc[m][n][r] + bv;
        if (ACT == 1) v = v / (1.f + __expf(-v));
        if (OUT == 0)
          ((float*)Cout)[(size_t)(grb + r) * N + gc] = v;
        else
          ((bf16_t*)Cout)[(size_t)(grb + r) * N + gc] = (bf16_t)v;
      }
    }
  }
}

// ---------------- block-diagonal An GEMM (BK=64, swizzled, XCD) ------------
__global__ __launch_bounds__(256) void an_gemm_kernel(
    const bf16_t* __restrict__ An, const bf16_t* __restrict__ xwT,
    const float* __restrict__ bias, bf16_t* __restrict__ outb) {
  __shared__ __align__(16) bf16_t Al[128 * 64];
  __shared__ __align__(16) bf16_t Bl[128 * 64];
  const int tid = threadIdx.x;
  const int lane = tid & 63;
  const int wave = tid >> 6;
  int2 sw = xcd_swizzle();
  const int row0 = sw.y * 128;  // node rows
  const int col0 = sw.x * 128;  // chan cols
  const int gr = row0 >> 8;     // graph
  f32x4v acc[4][4] = {};
  const int srow = wave * 8 + (lane >> 3);
  const int sslot = (lane & 7) ^ (lane >> 3);
  const bf16_t* aBase = An + (size_t)(row0 + srow) * 256 + sslot * 8;
  const bf16_t* bBase = xwT + (size_t)(col0 + srow) * NN + gr * 256 + sslot * 8;
  const int wm = (wave >> 1) * 64;
  const int wn = (wave & 1) * 64;
  const int fr = lane & 15;
  const int g = lane >> 4;
  const int f7 = fr & 7;
  for (int k0 = 0; k0 < 256; k0 += 64) {
#pragma unroll
    for (int i = 0; i < 4; ++i)
      gl_lds16(aBase + (size_t)(i * 32) * 256 + k0, Al + i * 2048 + wave * 512);
#pragma unroll
    for (int i = 0; i < 4; ++i)
      gl_lds16(bBase + (size_t)(i * 32) * NN + k0, Bl + i * 2048 + wave * 512);
    __syncthreads();
#pragma unroll
    for (int s = 0; s < 2; ++s) {
      const int sl = ((s * 4 + g) ^ f7) * 8;
      bf16x8 af[4], bfv[4];
#pragma unroll
      for (int m = 0; m < 4; ++m)
        af[m] = *(const bf16x8*)(Al + (wm + m * 16 + fr) * 64 + sl);
#pragma unroll
      for (int n = 0; n < 4; ++n)
        bfv[n] = *(const bf16x8*)(Bl + (wn + n * 16 + fr) * 64 + sl);
#pragma unroll
      for (int m = 0; m < 4; ++m)
#pragma unroll
        for (int n = 0; n < 4; ++n)
          acc[m][n] = __builtin_amdgcn_mfma_f32_16x16x32_bf16(af[m], bfv[n],
                                                              acc[m][n], 0, 0, 0);
    }
    __syncthreads();
  }
  const int fq = (lane >> 4) * 4;
#pragma unroll
  for (int m = 0; m < 4; ++m) {
    int grb = row0 + wm + m * 16 + fq;
#pragma unroll
    for (int n = 0; n < 4; ++n) {
      int gc = col0 + wn + n * 16 + fr;
      float bv = bias[gc];
#pragma unroll
      for (int r = 0; r < 4; ++r)
        outb[(size_t)(grb + r) * (2 * CC) + gc] = (bf16_t)(acc[m][n][r] + bv);
    }
  }
}

// ---------------- layernorm fused kernels ----------------

__device__ inline void block_reduce2(float& s, float& q, float* red) {
#pragma unroll
  for (int off = 32; off >= 1; off >>= 1) {
    s += __shfl_xor(s, off, 64);
    q += __shfl_xor(q, off, 64);
  }
  int wid = threadIdx.x >> 6;
  if ((threadIdx.x & 63) == 0) { red[wid * 2] = s; red[wid * 2 + 1] = q; }
  __syncthreads();
  s = red[0] + red[2] + red[4] + red[6];
  q = red[1] + red[3] + red[5] + red[7];
}

// out = LN(A + B) * g + be ; IA/IB: 1 = bf16 input; WF: 1 = f32 out, else bf16
template <int IA, int IB, int WF>
__global__ __launch_bounds__(256) void ln_addT_kernel(
    const void* __restrict__ A, const void* __restrict__ Bv,
    const float* __restrict__ g, const float* __restrict__ be,
    float* __restrict__ outf, bf16_t* __restrict__ outb) {
  int row = blockIdx.x, tid = threadIdx.x, c0 = tid * 2;
  __shared__ float red[8];
  float2 a = IA ? ldb2((const bf16_t*)A + (size_t)row * CC + c0)
                : *(const float2*)((const float*)A + (size_t)row * CC + c0);
  float2 b = IB ? ldb2((const bf16_t*)Bv + (size_t)row * CC + c0)
                : *(const float2*)((const float*)Bv + (size_t)row * CC + c0);
  float x0 = a.x + b.x, x1 = a.y + b.y;
  float s = x0 + x1, q = x0 * x0 + x1 * x1;
  block_reduce2(s, q, red);
  float mean = s * (1.f / CC);
  float var = q * (1.f / CC) - mean * mean;
  float rs = rsqrtf(var + 1e-5f);
  float o0 = (x0 - mean) * rs * g[c0] + be[c0];
  float o1 = (x1 - mean) * rs * g[c0 + 1] + be[c0 + 1];
  if (WF) {
    *(float2*)(outf + (size_t)row * CC + c0) = make_float2(o0, o1);
  } else {
    outb[(size_t)row * CC + c0] = (bf16_t)o0;
    outb[(size_t)row * CC + c0 + 1] = (bf16_t)o1;
  }
}

// gate+mix+LN+relu+residual; bf16 inputs (gpre, xc|ef), f32 x residual; bf16 out
__global__ __launch_bounds__(256) void ln_gate_kernel(
    const bf16_t* __restrict__ gpreb, const float* __restrict__ gate_b,
    const bf16_t* __restrict__ xcef, const float* __restrict__ n1g,
    const float* __restrict__ n1b, const float* __restrict__ xin,
    bf16_t* __restrict__ x2b) {
  int row = blockIdx.x, tid = threadIdx.x, c0 = tid * 2;
  __shared__ float red[8];
  float2 gp = ldb2(gpreb + (size_t)row * CC + c0);
  float2 xcv = ldb2(xcef + (size_t)row * (2 * CC) + c0);
  float2 efv = ldb2(xcef + (size_t)row * (2 * CC) + CC + c0);
  float g0 = 1.f / (1.f + __expf(-(gp.x + gate_b[c0])));
  float g1 = 1.f / (1.f + __expf(-(gp.y + gate_b[c0 + 1])));
  float x0 = g0 * xcv.x + (1.f - g0) * efv.x;
  float x1 = g1 * xcv.y + (1.f - g1) * efv.y;
  float s = x0 + x1, q = x0 * x0 + x1 * x1;
  block_reduce2(s, q, red);
  float mean = s * (1.f / CC);
  float var = q * (1.f / CC) - mean * mean;
  float rs = rsqrtf(var + 1e-5f);
  float2 xi = *(const float2*)(xin + (size_t)row * CC + c0);
  float o0 = fmaxf((x0 - mean) * rs * n1g[c0] + n1b[c0], 0.f) + xi.x;
  float o1 = fmaxf((x1 - mean) * rs * n1g[c0 + 1] + n1b[c0 + 1], 0.f) + xi.y;
  x2b[(size_t)row * CC + c0] = (bf16_t)o0;
  x2b[(size_t)row * CC + c0 + 1] = (bf16_t)o1;
}

// ---------------- V^T pack (pre-swizzled + pi-permuted K for attn) ---------
__global__ __launch_bounds__(256) void vt_pack_kernel(const bf16_t* __restrict__ qkvb,
                                                      bf16_t* __restrict__ vt) {
  int b = blockIdx.x >> 3, h = blockIdx.x & 7;
  int nb = b * 256;
  size_t voff = 1024 + (size_t)h * 64;
  char* out = (char*)(vt + (size_t)blockIdx.x * (64 * 256));
  __shared__ bf16_t tile[64][80];
  int tid = threadIdx.x;
  for (int kb = 0; kb < 4; ++kb) {
    __syncthreads();
#pragma unroll
    for (int p = 0; p < 2; ++p) {
      int k = p * 32 + (tid >> 3);
      int d8 = tid & 7;
      bf16x8 v = *(const bf16x8*)(qkvb + (size_t)(nb + kb * 64 + k) * 1536 + voff + d8 * 8);
      *(bf16x8*)(&tile[k][d8 * 8]) = v;
    }
    __syncthreads();
#pragma unroll
    for (int p = 0; p < 2; ++p) {
      int d = p * 32 + (tid >> 3);
      int k8 = tid & 7;
      bf16x8 v;
#pragma unroll
      for (int j = 0; j < 8; ++j) {
        int pos = k8 * 8 + j;
        int sl = pos & 31;
        int srck = (pos & 32) + ((sl >> 3) << 2) + (sl & 3) + (((sl >> 2) & 1) << 4);
        v[j] = tile[srck][d];
      }
      int byteoff = d * 512 + ((kb * 128 + k8 * 16) ^ ((d & 7) << 4));
      *(bf16x8*)(out + byteoff) = v;
    }
  }
}

// ---------------- MFMA attention (shuffle-free PV) ----------------
__global__ __launch_bounds__(256, 2) void attn_mfma_kernel(
    const bf16_t* __restrict__ qkvb, const bf16_t* __restrict__ vt,
    bf16_t* __restrict__ o) {
  const int b = blockIdx.x >> 3;
  const int h = blockIdx.x & 7;
  const int nb = b * 256;
  const int tid = threadIdx.x;
  const int lane = tid & 63;
  const int wv = tid >> 6;
  const int l15 = lane & 15;
  const int g = lane >> 4;
  const int swzk = (l15 & 7) << 4;
  __shared__ __align__(16) bf16_t Klds[256 * 64];
  __shared__ __align__(16) bf16_t Vtlds[64 * 256];
  const size_t qoff = (size_t)h * 64;
  const size_t koff = 512 + (size_t)h * 64;

  {
    const int dcol = 16 * ((tid & 7) ^ ((tid >> 3) & 7));
    const bf16_t* srcb = qkvb + koff + (dcol >> 1);
#pragma unroll
    for (int i = 0; i < 8; ++i) {
      int k = i * 32 + (tid >> 3);
      gl_lds16(srcb + (size_t)(nb + k) * 1536, Klds + ((i * 4096 + wv * 1024) >> 1));
    }
  }
  {
    const bf16_t* vsrc = vt + (size_t)blockIdx.x * (64 * 256);
#pragma unroll
    for (int i = 0; i < 8; ++i) {
      int base = i * 4096 + wv * 1024;
      gl_lds16(vsrc + ((base >> 1) + lane * 8), Vtlds + (base >> 1));
    }
  }

  bf16x8 qf[4][2];
#pragma unroll
  for (int n = 0; n < 4; ++n) {
    const bf16_t* qp = qkvb + (size_t)(nb + wv * 64 + 16 * n + l15) * 1536 + qoff + g * 8;
    qf[n][0] = *(const bf16x8*)(qp);
    qf[n][1] = *(const bf16x8*)(qp + 32);
  }

  __syncthreads();

  f32x4v oacc[4][4] = {};
  float mrun[4] = {-1e30f, -1e30f, -1e30f, -1e30f};
  float lrun[4] = {0.f, 0.f, 0.f, 0.f};

  for (int kc = 0; kc < 4; ++kc) {
    f32x4v sacc[4][4] = {};
    const int kb128 = (kc * 64 + l15) * 128;
#pragma unroll
    for (int m = 0; m < 4; ++m) {
      bf16x8 a0 = *(const bf16x8*)(Klds + ((kb128 + m * 2048 + ((g * 16) ^ swzk)) >> 1));
      bf16x8 a1 =
          *(const bf16x8*)(Klds + ((kb128 + m * 2048 + ((64 + g * 16) ^ swzk)) >> 1));
#pragma unroll
      for (int n = 0; n < 4; ++n) {
        sacc[m][n] = __builtin_amdgcn_mfma_f32_16x16x32_bf16(a0, qf[n][0], sacc[m][n], 0, 0, 0);
        sacc[m][n] = __builtin_amdgcn_mfma_f32_16x16x32_bf16(a1, qf[n][1], sacc[m][n], 0, 0, 0);
      }
    }
    uint2 pb[4][4];
#pragma unroll
    for (int n = 0; n < 4; ++n) {
      float mx = sacc[0][n][0];
#pragma unroll
      for (int m = 0; m < 4; ++m)
#pragma unroll
        for (int r = 0; r < 4; ++r) mx = fmaxf(mx, sacc[m][n][r]);
      mx = fmaxf(mx, __shfl_xor(mx, 16));
      mx = fmaxf(mx, __shfl_xor(mx, 32));
      float mnew = fmaxf(mrun[n], mx);
      float c = __expf((mrun[n] - mnew) * 0.125f);
      mrun[n] = mnew;
      float s = 0.f;
#pragma unroll
      for (int m = 0; m < 4; ++m) {
        float p0 = __expf((sacc[m][n][0] - mnew) * 0.125f);
        float p1 = __expf((sacc[m][n][1] - mnew) * 0.125f);
        float p2 = __expf((sacc[m][n][2] - mnew) * 0.125f);
        float p3 = __expf((sacc[m][n][3] - mnew) * 0.125f);
        s += (p0 + p1) + (p2 + p3);
        union { bf16x4 v; uint2 u; } cv;
        cv.v[0] = (bf16_t)p0; cv.v[1] = (bf16_t)p1;
        cv.v[2] = (bf16_t)p2; cv.v[3] = (bf16_t)p3;
        pb[m][n] = cv.u;
      }
      s += __shfl_xor(s, 16);
      s += __shfl_xor(s, 32);
      lrun[n] = lrun[n] * c + s;
#pragma unroll
      for (int m = 0; m < 4; ++m)
#pragma unroll
        for (int r = 0; r < 4; ++r) oacc[m][n][r] *= c;
    }
#pragma unroll
    for (int h2 = 0; h2 < 2; ++h2) {
      bf16x8 vf[4];
#pragma unroll
      for (int m = 0; m < 4; ++m)
        vf[m] = *(const bf16x8*)(Vtlds + (((16 * m + l15) * 512 +
                                          ((kc * 128 + h2 * 64 + g * 16) ^ swzk)) >> 1));
#pragma unroll
      for (int n = 0; n < 4; ++n) {
        union { uint2 u[2]; bf16x8 v; } pf;
        pf.u[0] = pb[2 * h2][n];
        pf.u[1] = pb[2 * h2 + 1][n];
#pragma unroll
        for (int m = 0; m < 4; ++m)
          oacc[m][n] =
              __builtin_amdgcn_mfma_f32_16x16x32_bf16(vf[m], pf.v, oacc[m][n], 0, 0, 0);
      }
    }
  }
  float inv[4];
#pragma unroll
  for (int n = 0; n < 4; ++n) inv[n] = 1.0f / lrun[n];
#pragma unroll
  for (int m = 0; m < 4; ++m)
#pragma unroll
    for (int n = 0; n < 4; ++n) {
      bf16x4 pk;
#pragma unroll
      for (int r = 0; r < 4; ++r) pk[r] = (bf16_t)(oacc[m][n][r] * inv[n]);
      *(bf16x4*)(o + (size_t)(nb + wv * 64 + 16 * n + l15) * 512 + h * 64 + 16 * m +
                 4 * g) = pk;
    }
}

// ---------------- launch ----------------

static inline char* alignp(char* p, size_t a) {
  return (char*)(((uintptr_t)p + a - 1) & ~(uintptr_t)(a - 1));
}

extern "C" void kernel_launch(void* const* d_in, const int* in_sizes, int n_in,
                              void* d_out, int out_size, void* d_ws, size_t ws_size,
                              hipStream_t stream) {
  const float* x = (const float*)d_in[0];
  const float* edge_attr = (const float*)d_in[1];
  const float* gcn_w = (const float*)d_in[2];
  const float* gcn_b = (const float*)d_in[3];
  const float* ep_w = (const float*)d_in[4];
  const float* ep_b = (const float*)d_in[5];
  const float* gate_w = (const float*)d_in[6];
  const float* gate_b = (const float*)d_in[7];
  const float* n1_g = (const float*)d_in[8];
  const float* n1_b = (const float*)d_in[9];
  const float* in_w = (const float*)d_in[10];
  const float* in_b = (const float*)d_in[11];
  const float* out_w = (const float*)d_in[12];
  const float* out_b = (const float*)d_in[13];
  const float* tn_g = (const float*)d_in[14];
  const float* tn_b = (const float*)d_in[15];
  const float* m_w1 = (const float*)d_in[16];
  const float* m_b1 = (const float*)d_in[17];
  const float* m_w2 = (const float*)d_in[18];
  const float* m_b2 = (const float*)d_in[19];
  const float* fn_g = (const float*)d_in[20];
  const float* fn_b = (const float*)d_in[21];
  const int* eidx = (const int*)d_in[22];
  const int* src = eidx;
  const int* dst = eidx + EE;

  float* ws = (float*)d_ws;
  float* R1 = ws;
  float* R2 = R1 + (size_t)NN * 3 * CC;
  float* R3 = R2 + (size_t)NN * CC;
  float* R4 = R3 + (size_t)NN * CC;
  float* dinv = R4 + (size_t)NN * CC;
  int* ip = (int*)(dinv + NN);
  int* ghist = ip;      ip += 64;
  int* gstart = ip;     ip += 65;
  int* gcur = ip;       ip += 64;
  int* elist_src = ip;  ip += EE;
  int* nid_src = ip;    ip += EE + 32;
  int* start_src = ip;  ip += NN + 1;
  int* start_dst = ip;  ip += NN + 1;
  char* bp = alignp((char*)ip, 64);
  int2* grec = (int2*)bp;             bp += (size_t)EE * 8;
  float* ewg = (float*)bp;            bp += (size_t)EE * 4;
  float2* dstrec = (float2*)bp;       bp += (size_t)EE * 8;
  bf16_t* x2b = (bf16_t*)bp;          bp += (size_t)NN * CC * 2;
  bf16_t* gcn_wt = (bf16_t*)bp;       bp += (size_t)CC * CC * 2;
  bf16_t* gate_wt = (bf16_t*)bp;      bp += (size_t)CC * 2 * CC * 2;
  bf16_t* in_wt = (bf16_t*)bp;        bp += (size_t)3 * CC * CC * 2;
  bf16_t* out_wt = (bf16_t*)bp;       bp += (size_t)CC * CC * 2;
  bf16_t* m_w1t = (bf16_t*)bp;        bp += (size_t)2 * CC * CC * 2;
  bf16_t* m_w2t = (bf16_t*)bp;        bp += (size_t)CC * 2 * CC * 2;

  bf16_t* xb = (bf16_t*)R1;      // bf16(x)
  bf16_t* xcefb = (bf16_t*)R1;   // [x_conv | ef] bf16 N x 2C
  bf16_t* qkvb = (bf16_t*)R1;    // qkv bf16 N x 1536
  bf16_t* hb = (bf16_t*)R1;      // mlp hidden bf16 N x 2C
  bf16_t* eacsr = (bf16_t*)((char*)R1 + (size_t)64 * 1024 * 1024);  // 16.8MB
  bf16_t* xwT = (bf16_t*)R2;     // (x@gcn_w)^T bf16 [512][16384]
  bf16_t* gpreb = (bf16_t*)R2;   // gate pre-act bf16 (after xwT dead)
  bf16_t* ob = (bf16_t*)R2;      // attn out bf16 (first half of R2)
  bf16_t* vt = ob + (size_t)NN * CC;  // V^T packed (second half of R2)
  bf16_t* x3b = (bf16_t*)R2;     // bf16(x3) (after ob dead)
  bf16_t* AnFull = (bf16_t*)R3;  // dense adjacency bf16 [16384][256] (8MB)
  bf16_t* oprjb = (bf16_t*)R4;   // out-proj bf16
  float* yf = R4;                // mlp2 f32 out (after oprjb dead)

  // --- edge prep ---
  init_kernel<<<1, 256, 0, stream>>>(ghist, nid_src, eacsr);
  edge_pass1<<<EE / 256, 256, 0, stream>>>(dst, ghist);
  gexscan_kernel<<<1, 64, 0, stream>>>(ghist, gstart, gcur);
  graph_scatter_kernel<<<EE / 2048, 256, 0, stream>>>(src, dst, edge_attr, gcur,
                                                      grec, ewg);
  graph_sort2_kernel<<<128, 1024, 0, stream>>>(grec, ewg, gstart, elist_src, nid_src,
                                               start_src, dstrec, start_dst, dinv);
  ea_gather_kernel<<<(EE * 2 + 255) / 256, 256, 0, stream>>>(edge_attr, elist_src,
                                                             eacsr);
  an_build_kernel<<<128, 256, 0, stream>>>(dstrec, start_dst, dinv, AnFull);

  // --- weight transposes ---
  wt_kernel<<<dim3(CC / 32, CC / 32), 256, 0, stream>>>(gcn_w, gcn_wt, CC, CC);
  wt_kernel<<<dim3(CC / 32, 2 * CC / 32), 256, 0, stream>>>(gate_w, gate_wt, 2 * CC, CC);
  wt_kernel<<<dim3(3 * CC / 32, CC / 32), 256, 0, stream>>>(in_w, in_wt, CC, 3 * CC);
  wt_kernel<<<dim3(CC / 32, CC / 32), 256, 0, stream>>>(out_w, out_wt, CC, CC);
  wt_kernel<<<dim3(2 * CC / 32, CC / 32), 256, 0, stream>>>(m_w1, m_w1t, CC, 2 * CC);
  wt_kernel<<<dim3(CC / 32, 2 * CC / 32), 256, 0, stream>>>(m_w2, m_w2t, 2 * CC, CC);

  // --- GCN conv: xwT = (x @ gcn_w)^T via flipped GEMM, then dense An GEMM ---
  cvt_bf16_kernel<<<(NN * CC / 4 + 255) / 256, 256, 0, stream>>>(x, xb, NN * CC / 4);
  gemm_bf16_kernel<0, 1><<<dim3(NN / 128, CC / 128), 256, 0, stream>>>(
      gcn_wt, xb, nullptr, xwT, CC, NN, CC);
  an_gemm_kernel<<<dim3(CC / 128, NN / 128), 256, 0, stream>>>(AnFull, xwT, gcn_b,
                                                               xcefb);
  ef_mfma_kernel<<<NN / 16, 512, 0, stream>>>(eacsr, ep_w, ep_b, nid_src, start_src,
                                              xcefb);
  dim3 gA(CC / 128, NN / 128);
  gemm_bf16_kernel<0, 1><<<gA, 256, 0, stream>>>(xcefb, gate_wt, nullptr, gpreb, NN,
                                                 CC, 2 * CC);
  ln_gate_kernel<<<NN, 256, 0, stream>>>(gpreb, gate_b, xcefb, n1_g, n1_b, x, x2b);

  // --- MHA ---
  dim3 gQ(3 * CC / 128, NN / 128);
  gemm_bf16_kernel<0, 1><<<gQ, 256, 0, stream>>>(x2b, in_wt, in_b, qkvb, NN, 3 * CC, CC);
  vt_pack_kernel<<<BB * HH, 256, 0, stream>>>(qkvb, vt);
  attn_mfma_kernel<<<BB * HH, 256, 0, stream>>>(qkvb, vt, ob);
  gemm_bf16_kernel<0, 1><<<gA, 256, 0, stream>>>(ob, out_wt, out_b, oprjb, NN, CC, CC);
  ln_addT_kernel<1, 1, 0><<<NN, 256, 0, stream>>>(x2b, oprjb, tn_g, tn_b, nullptr, x3b);

  // --- MLP ---
  dim3 gH(2 * CC / 128, NN / 128);
  gemm_bf16_kernel<1, 1><<<gH, 256, 0, stream>>>(x3b, m_w1t, m_b1, hb, NN, 2 * CC, CC);
  gemm_bf16_kernel<0, 0><<<gA, 256, 0, stream>>>(hb, m_w2t, m_b2, yf, NN, CC, 2 * CC);
  ln_addT_kernel<1, 0, 1><<<NN, 256, 0, stream>>>(x3b, yf, fn_g, fn_b, (float*)d_out,
                                                  nullptr);
}

// Round 17
// 443.447 us; speedup vs baseline: 1.0105x; 1.0105x over previous
//
#include <hip/hip_runtime.h>

#define NN 16384
#define CC 512
#define EE 524288
#define BB 64
#define HH 8
#define EFD 16
#define GEMAXE 10240

typedef __bf16 bf16_t;
typedef __bf16 bf16x4 __attribute__((ext_vector_type(4)));
typedef __bf16 bf16x8 __attribute__((ext_vector_type(8)));
typedef float f32x4v __attribute__((ext_vector_type(4)));

__device__ __forceinline__ float2 ldb2(const bf16_t* p) {
  unsigned w = *(const unsigned*)p;
  return make_float2(__uint_as_float(w << 16), __uint_as_float(w & 0xFFFF0000u));
}

// XCD-aware chunked swizzle (nwg % 8 == 0 for all our grids)
__device__ __forceinline__ int2 xcd_swizzle() {
  int nwg = gridDim.x * gridDim.y;
  int bid = blockIdx.y * gridDim.x + blockIdx.x;
  int wg = (bid & 7) * (nwg >> 3) + (bid >> 3);
  return make_int2(wg % gridDim.x, wg / gridDim.x);
}

// ---------------- init / edge pre-pass ----------------

__global__ void init_kernel(int* ghist, int* nid_src, bf16_t* eacsr) {
  int i = threadIdx.x;
  if (i < 64) ghist[i] = 0;
  if (i < 32) nid_src[EE + i] = -1;               // pad for ef chunk tail
  ((int*)(eacsr + (size_t)EE * 16))[i] = 0;       // zero eacsr pad rows (256 ints)
}

// per-graph histogram only (LDS-aggregated)
__global__ __launch_bounds__(256) void edge_pass1(const int* __restrict__ dst,
                                                  int* ghist) {
  __shared__ int h[64];
  int tid = threadIdx.x;
  if (tid < 64) h[tid] = 0;
  __syncthreads();
  int e = blockIdx.x * 256 + tid;  // EE % 256 == 0
  atomicAdd(&h[dst[e] >> 8], 1);
  __syncthreads();
  if (tid < 64 && h[tid]) atomicAdd(&ghist[tid], h[tid]);
}

__global__ void gexscan_kernel(const int* __restrict__ ghist, int* __restrict__ gstart,
                               int* __restrict__ gcur) {
  if (threadIdx.x == 0) {
    int s = 0;
    for (int g = 0; g < 64; ++g) { gstart[g] = s; gcur[g] = s; s += ghist[g]; }
    gstart[64] = s;
  }
}

// bucket edges by graph with block-aggregated offsets; emit packed records.
// ew computed inline from ea (single pass over edge_attr).
__global__ __launch_bounds__(256) void graph_scatter_kernel(
    const int* __restrict__ src, const int* __restrict__ dst,
    const float* __restrict__ ea, int* gcur, int2* __restrict__ grec,
    float* __restrict__ ewg) {
  __shared__ int h[64], base[64], h2[64];
  int tid = threadIdx.x;
  if (tid < 64) { h[tid] = 0; h2[tid] = 0; }
  __syncthreads();
  int e0 = blockIdx.x * 2048;
  int gloc[8];
#pragma unroll
  for (int k = 0; k < 8; ++k) {
    gloc[k] = dst[e0 + k * 256 + tid] >> 8;
    atomicAdd(&h[gloc[k]], 1);
  }
  __syncthreads();
  if (tid < 64) base[tid] = h[tid] ? atomicAdd(&gcur[tid], h[tid]) : 0;
  __syncthreads();
#pragma unroll
  for (int k = 0; k < 8; ++k) {
    int e = e0 + k * 256 + tid;
    int g = gloc[k];
    int p = atomicAdd(&h2[g], 1);
    int pos = base[g] + p;
    int ls = src[e] & 255;
    int ld = dst[e] & 255;
    grec[pos] = make_int2(e | (ls << 19), ld);
    const float4* pa = (const float4*)(ea + (size_t)e * EFD);
    float s = 0.f;
#pragma unroll
    for (int q = 0; q < 4; ++q) {
      float4 v = pa[q];
      s += v.x * v.x + v.y * v.y + v.z * v.z + v.w * v.w;
    }
    ewg[pos] = sqrtf(s);
  }
}

// per-graph LDS counting sort, 128 blocks: blockIdx<64 -> DST pass, else SRC.
__global__ __launch_bounds__(1024) void graph_sort2_kernel(
    const int2* __restrict__ grec, const float* __restrict__ ewg,
    const int* __restrict__ gstart, int* __restrict__ elist_src,
    int* __restrict__ nid_src, int* __restrict__ start_src,
    float2* __restrict__ dstrec, int* __restrict__ start_dst,
    float* __restrict__ dinv) {
  __shared__ int lbuf[GEMAXE];
  __shared__ unsigned short sl[GEMAXE];
  __shared__ float ewl[GEMAXE];
  __shared__ int h[256], hx[256], h2[256];
  __shared__ float fdinv[256];
  const int g = blockIdx.x & 63;
  const int tid = threadIdx.x;
  const int gs = gstart[g];
  const int cnt = gstart[g + 1] - gs;
  if (tid < 256) { h[tid] = 0; h2[tid] = 0; }
  __syncthreads();
  if (blockIdx.x < 64) {
    for (int i = tid; i < cnt; i += 1024) {
      int2 r = grec[gs + i];
      int ld = r.y;
      sl[i] = (unsigned short)(((r.x >> 19) & 255) | (ld << 8));
      ewl[i] = ewg[gs + i];
      atomicAdd(&h[ld], 1);
    }
    __syncthreads();
    int myc = (tid < 256) ? h[tid] : 0;
    for (int off = 1; off < 256; off <<= 1) {
      int v = (tid < 256 && tid >= off) ? h[tid - off] : 0;
      __syncthreads();
      if (tid < 256) h[tid] += v;
      __syncthreads();
    }
    if (tid < 256) {
      hx[tid] = h[tid] - myc;
      start_dst[g * 256 + tid] = gs + hx[tid];
    }
    if (g == 63 && tid == 0) start_dst[NN] = EE;
    __syncthreads();
    for (int i = tid; i < cnt; i += 1024) {
      int ld = sl[i] >> 8;
      int p = hx[ld] + atomicAdd(&h2[ld], 1);
      lbuf[p] = i;
    }
    __syncthreads();
    if (tid < 256) {
      float dg = 1.0f;
      int s0 = hx[tid], e0 = s0 + myc;
      for (int i = s0; i < e0; ++i) dg += ewl[lbuf[i]];
      float dv = rsqrtf(fmaxf(dg, 1e-12f));
      fdinv[tid] = dv;
      dinv[g * 256 + tid] = dv;
    }
    __syncthreads();
    for (int p = tid; p < cnt; p += 1024) {
      int i = lbuf[p];
      int ls = sl[i] & 255;
      int ld = sl[i] >> 8;
      dstrec[gs + p] =
          make_float2(fdinv[ls] * ewl[i] * fdinv[ld], __int_as_float(ls));
    }
  } else {
    int* wb = (int*)ewl;
    for (int i = tid; i < cnt; i += 1024) {
      int w = grec[gs + i].x;
      wb[i] = w;
      atomicAdd(&h[w >> 19], 1);
    }
    __syncthreads();
    int myc = (tid < 256) ? h[tid] : 0;
    for (int off = 1; off < 256; off <<= 1) {
      int v = (tid < 256 && tid >= off) ? h[tid - off] : 0;
      __syncthreads();
      if (tid < 256) h[tid] += v;
      __syncthreads();
    }
    if (tid < 256) {
      hx[tid] = h[tid] - myc;
      start_src[g * 256 + tid] = gs + hx[tid];
    }
    if (g == 63 && tid == 0) start_src[NN] = EE;
    __syncthreads();
    for (int i = tid; i < cnt; i += 1024) {
      int w = wb[i];
      int ls = w >> 19;
      int p = hx[ls] + atomicAdd(&h2[ls], 1);
      lbuf[p] = w;
    }
    __syncthreads();
    for (int p = tid; p < cnt; p += 1024) {
      int w = lbuf[p];
      elist_src[gs + p] = w & 0x7FFFF;
      nid_src[gs + p] = g * 256 + (w >> 19);
    }
  }
}

// gather edge_attr rows into CSR order as bf16
__global__ void ea_gather_kernel(const float* __restrict__ ea,
                                 const int* __restrict__ elist,
                                 bf16_t* __restrict__ eacsr) {
  int idx = blockIdx.x * 256 + threadIdx.x;
  if (idx >= EE * 2) return;
  int pos = idx >> 1, half = idx & 1;
  int e = elist[pos];
  const f32x4v* p = (const f32x4v*)(ea + (size_t)e * EFD + half * 8);
  f32x4v u0 = p[0], u1 = p[1];
  bf16x8 f;
#pragma unroll
  for (int r = 0; r < 4; ++r) {
    f[r] = (bf16_t)u0[r];
    f[4 + r] = (bf16_t)u1[r];
  }
  *(bf16x8*)(eacsr + (size_t)pos * 16 + half * 8) = f;
}

// ---------------- dense per-graph adjacency build ----------------
__global__ __launch_bounds__(256) void an_build_kernel(
    const float2* __restrict__ dstrec, const int* __restrict__ start_dst,
    const float* __restrict__ dinv, bf16_t* __restrict__ An) {
  __shared__ float AnS[128][256];  // 128 KB
  const int g = blockIdx.x >> 1, h = blockIdx.x & 1;
  const int tid = threadIdx.x;
  float4* az = (float4*)&AnS[0][0];
  for (int i = tid; i < 128 * 256 / 4; i += 256)
    az[i] = make_float4(0.f, 0.f, 0.f, 0.f);
  __syncthreads();
  const int nbase = g * 256 + h * 128;
  if (tid < 128) {
    int node = nbase + tid;
    int st = start_dst[node], en = start_dst[node + 1];
    float* row = AnS[tid];
    for (int p = st; p < en; ++p) {
      float2 r = dstrec[p];
      row[__float_as_int(r.y)] += r.x;
    }
    float dv = dinv[node];
    row[h * 128 + tid] += dv * dv;
  }
  __syncthreads();
  bf16_t* out = An + (size_t)nbase * 256;
  const float* s0 = &AnS[0][0];
  for (int i = tid; i < 128 * 256 / 8; i += 256) {
    bf16x8 v;
#pragma unroll
    for (int r = 0; r < 8; ++r) v[r] = (bf16_t)s0[i * 8 + r];
    *(bf16x8*)(out + i * 8) = v;
  }
}

// ---------------- conversions ----------------

__global__ void cvt_bf16_kernel(const float* __restrict__ in, bf16_t* __restrict__ out,
                                int n4) {
  int i = blockIdx.x * 256 + threadIdx.x;
  if (i >= n4) return;
  float4 v = ((const float4*)in)[i];
  bf16x4 o;
  o[0] = (bf16_t)v.x; o[1] = (bf16_t)v.y; o[2] = (bf16_t)v.z; o[3] = (bf16_t)v.w;
  ((bf16x4*)out)[i] = o;
}

// W: f32 [K][N] row-major -> Wt: bf16 [N][K] row-major
__global__ __launch_bounds__(256) void wt_kernel(const float* __restrict__ W,
                                                 bf16_t* __restrict__ Wt, int K, int N) {
  __shared__ float tile[32][33];
  int bx = blockIdx.x * 32;
  int by = blockIdx.y * 32;
  int tx = threadIdx.x & 31, ty = threadIdx.x >> 5;
#pragma unroll
  for (int i = 0; i < 32; i += 8)
    tile[ty + i][tx] = W[(size_t)(by + ty + i) * N + bx + tx];
  __syncthreads();
#pragma unroll
  for (int i = 0; i < 32; i += 8)
    Wt[(size_t)(bx + ty + i) * K + by + tx] = (bf16_t)tile[tx][ty + i];
}

// ---------------- edge projection via double-MFMA (8 waves x 64 cols) ------
__global__ __launch_bounds__(512) void ef_mfma_kernel(
    const bf16_t* __restrict__ eacsr, const float* __restrict__ ep_w,
    const float* __restrict__ ep_b, const int* __restrict__ nid,
    const int* __restrict__ start, bf16_t* __restrict__ efb) {
  const int tid = threadIdx.x;
  const int lane = tid & 63;
  const int wv = tid >> 6;      // 0..7
  const int l15 = lane & 15;
  const int g = lane >> 4;
  const int n0 = blockIdx.x * 16;
  const int cbase = wv * 64;

  bf16x8 wfr[4];
#pragma unroll
  for (int t = 0; t < 4; ++t) {
    bf16x8 f = {};
    int c = cbase + t * 16 + l15;
    if (g < 2) {
#pragma unroll
      for (int j = 0; j < 8; ++j) f[j] = (bf16_t)ep_w[(g * 8 + j) * CC + c];
    } else if (g == 2) {
      f[0] = (bf16_t)ep_b[c];
    }
    wfr[t] = f;
  }

  const int st = start[n0];
  const int en = start[n0 + 16];
  const int tgt = n0 + l15;

  f32x4v eacc[4] = {};

  for (int cb = st; cb < en; cb += 32) {
    bf16x8 af[2];
#pragma unroll
    for (int mE = 0; mE < 2; ++mE) {
      bf16x8 f = {};
      if (g < 2) {
        f = *(const bf16x8*)(eacsr + (size_t)(cb + mE * 16 + l15) * 16 + g * 8);
      } else if (g == 2) {
        f[0] = (bf16_t)1.0f;
      }
      af[mE] = f;
    }
    int4 idlo = *(const int4*)(nid + cb + g * 4);
    int4 idhi = *(const int4*)(nid + cb + 16 + g * 4);
    bf16x8 sf;
    sf[0] = (idlo.x == tgt) ? (bf16_t)1.0f : (bf16_t)0.0f;
    sf[1] = (idlo.y == tgt) ? (bf16_t)1.0f : (bf16_t)0.0f;
    sf[2] = (idlo.z == tgt) ? (bf16_t)1.0f : (bf16_t)0.0f;
    sf[3] = (idlo.w == tgt) ? (bf16_t)1.0f : (bf16_t)0.0f;
    sf[4] = (idhi.x == tgt) ? (bf16_t)1.0f : (bf16_t)0.0f;
    sf[5] = (idhi.y == tgt) ? (bf16_t)1.0f : (bf16_t)0.0f;
    sf[6] = (idhi.z == tgt) ? (bf16_t)1.0f : (bf16_t)0.0f;
    sf[7] = (idhi.w == tgt) ? (bf16_t)1.0f : (bf16_t)0.0f;
    __builtin_amdgcn_s_setprio(1);
#pragma unroll
    for (int t = 0; t < 4; ++t) {
      f32x4v s0 = {}, s1 = {};
      s0 = __builtin_amdgcn_mfma_f32_16x16x32_bf16(af[0], wfr[t], s0, 0, 0, 0);
      s1 = __builtin_amdgcn_mfma_f32_16x16x32_bf16(af[1], wfr[t], s1, 0, 0, 0);
      union { bf16x8 v; bf16x4 h[2]; } pf;
#pragma unroll
      for (int r = 0; r < 4; ++r) {
        pf.h[0][r] = (bf16_t)fmaxf(s0[r], 0.f);
        pf.h[1][r] = (bf16_t)fmaxf(s1[r], 0.f);
      }
      eacc[t] = __builtin_amdgcn_mfma_f32_16x16x32_bf16(sf, pf.v, eacc[t], 0, 0, 0);
    }
    __builtin_amdgcn_s_setprio(0);
  }
#pragma unroll
  for (int t = 0; t < 4; ++t) {
    int c = cbase + t * 16 + l15;
#pragma unroll
    for (int r = 0; r < 4; ++r) {
      int node = n0 + g * 4 + r;
      efb[(size_t)node * (2 * CC) + CC + c] = (bf16_t)eacc[t][r];
    }
  }
}

// ---------------- bf16 MFMA GEMM: BK=64, swizzled LDS, XCD swizzle ---------
__device__ __forceinline__ void gl_lds16(const bf16_t* g, bf16_t* l) {
  __builtin_amdgcn_global_load_lds(
      (const __attribute__((address_space(1))) void*)g,
      (__attribute__((address_space(3))) void*)l, 16, 0, 0);
}

// LDS [128][64] bf16 (128B rows), content swizzled: LDS slot sl of row r holds
// global k-slot sl^(r&7). Write: linear dest, pre-swizzled global source.
// Read: slot q at LDS slot q^(r&7). Conflict-free ds_read_b128 (2 lanes/bank).
template <int ACT, int OUT>
__global__ __launch_bounds__(256) void gemm_bf16_kernel(
    const bf16_t* __restrict__ A, const bf16_t* __restrict__ Bt,
    const float* __restrict__ bias, void* __restrict__ Cout, int M, int N, int K) {
  __shared__ __align__(16) bf16_t Al[128 * 64];
  __shared__ __align__(16) bf16_t Bl[128 * 64];
  const int tid = threadIdx.x;
  const int lane = tid & 63;
  const int wave = tid >> 6;
  int2 sw = xcd_swizzle();
  const int row0 = sw.y * 128;
  const int col0 = sw.x * 128;
  const int wm = (wave >> 1) * 64;
  const int wn = (wave & 1) * 64;
  f32x4v acc[4][4] = {};
  // staging: issue i covers rows i*32 + wave*8 + (lane>>3); slot = lane&7
  const int srow = wave * 8 + (lane >> 3);
  const int sslot = (lane & 7) ^ (lane >> 3);
  const bf16_t* aBase = A + (size_t)(row0 + srow) * K + sslot * 8;
  const bf16_t* bBase = Bt + (size_t)(col0 + srow) * K + sslot * 8;
  const int fr = lane & 15;
  const int g = lane >> 4;
  const int f7 = fr & 7;
  for (int k0 = 0; k0 < K; k0 += 64) {
#pragma unroll
    for (int i = 0; i < 4; ++i)
      gl_lds16(aBase + (size_t)(i * 32) * K + k0, Al + i * 2048 + wave * 512);
#pragma unroll
    for (int i = 0; i < 4; ++i)
      gl_lds16(bBase + (size_t)(i * 32) * K + k0, Bl + i * 2048 + wave * 512);
    __syncthreads();
#pragma unroll
    for (int s = 0; s < 2; ++s) {
      const int sl = ((s * 4 + g) ^ f7) * 8;
      bf16x8 af[4], bfv[4];
#pragma unroll
      for (int m = 0; m < 4; ++m)
        af[m] = *(const bf16x8*)(Al + (wm + m * 16 + fr) * 64 + sl);
#pragma unroll
      for (int n = 0; n < 4; ++n)
        bfv[n] = *(const bf16x8*)(Bl + (wn + n * 16 + fr) * 64 + sl);
#pragma unroll
      for (int m = 0; m < 4; ++m)
#pragma unroll
        for (int n = 0; n < 4; ++n)
          acc[m][n] = __builtin_amdgcn_mfma_f32_16x16x32_bf16(af[m], bfv[n],
                                                              acc[m][n], 0, 0, 0);
    }
    __syncthreads();
  }
  const int fq = (lane >> 4) * 4;
#pragma unroll
  for (int m = 0; m < 4; ++m) {
    int grb = row0 + wm + m * 16 + fq;
#pragma unroll
    for (int n = 0; n < 4; ++n) {
      int gc = col0 + wn + n * 16 + fr;
      float bv = bias ? bias[gc] : 0.f;
#pragma unroll
      for (int r = 0; r < 4; ++r) {
        float v = acc[m][n][r] + bv;
        if (ACT == 1) v = v / (1.f + __expf(-v));
        if (OUT == 0)
          ((float*)Cout)[(size_t)(grb + r) * N + gc] = v;
        else
          ((bf16_t*)Cout)[(size_t)(grb + r) * N + gc] = (bf16_t)v;
      }
    }
  }
}

// ---------------- block-diagonal An GEMM (BK=64, swizzled, XCD) ------------
__global__ __launch_bounds__(256) void an_gemm_kernel(
    const bf16_t* __restrict__ An, const bf16_t* __restrict__ xwT,
    const float* __restrict__ bias, bf16_t* __restrict__ outb) {
  __shared__ __align__(16) bf16_t Al[128 * 64];
  __shared__ __align__(16) bf16_t Bl[128 * 64];
  const int tid = threadIdx.x;
  const int lane = tid & 63;
  const int wave = tid >> 6;
  int2 sw = xcd_swizzle();
  const int row0 = sw.y * 128;  // node rows
  const int col0 = sw.x * 128;  // chan cols
  const int gr = row0 >> 8;     // graph
  f32x4v acc[4][4] = {};
  const int srow = wave * 8 + (lane >> 3);
  const int sslot = (lane & 7) ^ (lane >> 3);
  const bf16_t* aBase = An + (size_t)(row0 + srow) * 256 + sslot * 8;
  const bf16_t* bBase = xwT + (size_t)(col0 + srow) * NN + gr * 256 + sslot * 8;
  const int wm = (wave >> 1) * 64;
  const int wn = (wave & 1) * 64;
  const int fr = lane & 15;
  const int g = lane >> 4;
  const int f7 = fr & 7;
  for (int k0 = 0; k0 < 256; k0 += 64) {
#pragma unroll
    for (int i = 0; i < 4; ++i)
      gl_lds16(aBase + (size_t)(i * 32) * 256 + k0, Al + i * 2048 + wave * 512);
#pragma unroll
    for (int i = 0; i < 4; ++i)
      gl_lds16(bBase + (size_t)(i * 32) * NN + k0, Bl + i * 2048 + wave * 512);
    __syncthreads();
#pragma unroll
    for (int s = 0; s < 2; ++s) {
      const int sl = ((s * 4 + g) ^ f7) * 8;
      bf16x8 af[4], bfv[4];
#pragma unroll
      for (int m = 0; m < 4; ++m)
        af[m] = *(const bf16x8*)(Al + (wm + m * 16 + fr) * 64 + sl);
#pragma unroll
      for (int n = 0; n < 4; ++n)
        bfv[n] = *(const bf16x8*)(Bl + (wn + n * 16 + fr) * 64 + sl);
#pragma unroll
      for (int m = 0; m < 4; ++m)
#pragma unroll
        for (int n = 0; n < 4; ++n)
          acc[m][n] = __builtin_amdgcn_mfma_f32_16x16x32_bf16(af[m], bfv[n],
                                                              acc[m][n], 0, 0, 0);
    }
    __syncthreads();
  }
  const int fq = (lane >> 4) * 4;
#pragma unroll
  for (int m = 0; m < 4; ++m) {
    int grb = row0 + wm + m * 16 + fq;
#pragma unroll
    for (int n = 0; n < 4; ++n) {
      int gc = col0 + wn + n * 16 + fr;
      float bv = bias[gc];
#pragma unroll
      for (int r = 0; r < 4; ++r)
        outb[(size_t)(grb + r) * (2 * CC) + gc] = (bf16_t)(acc[m][n][r] + bv);
    }
  }
}

// ---------------- layernorm fused kernels ----------------

__device__ inline void block_reduce2(float& s, float& q, float* red) {
#pragma unroll
  for (int off = 32; off >= 1; off >>= 1) {
    s += __shfl_xor(s, off, 64);
    q += __shfl_xor(q, off, 64);
  }
  int wid = threadIdx.x >> 6;
  if ((threadIdx.x & 63) == 0) { red[wid * 2] = s; red[wid * 2 + 1] = q; }
  __syncthreads();
  s = red[0] + red[2] + red[4] + red[6];
  q = red[1] + red[3] + red[5] + red[7];
}

// out = LN(A + B) * g + be ; IA/IB: 1 = bf16 input; WF: 1 = f32 out, else bf16
template <int IA, int IB, int WF>
__global__ __launch_bounds__(256) void ln_addT_kernel(
    const void* __restrict__ A, const void* __restrict__ Bv,
    const float* __restrict__ g, const float* __restrict__ be,
    float* __restrict__ outf, bf16_t* __restrict__ outb) {
  int row = blockIdx.x, tid = threadIdx.x, c0 = tid * 2;
  __shared__ float red[8];
  float2 a = IA ? ldb2((const bf16_t*)A + (size_t)row * CC + c0)
                : *(const float2*)((const float*)A + (size_t)row * CC + c0);
  float2 b = IB ? ldb2((const bf16_t*)Bv + (size_t)row * CC + c0)
                : *(const float2*)((const float*)Bv + (size_t)row * CC + c0);
  float x0 = a.x + b.x, x1 = a.y + b.y;
  float s = x0 + x1, q = x0 * x0 + x1 * x1;
  block_reduce2(s, q, red);
  float mean = s * (1.f / CC);
  float var = q * (1.f / CC) - mean * mean;
  float rs = rsqrtf(var + 1e-5f);
  float o0 = (x0 - mean) * rs * g[c0] + be[c0];
  float o1 = (x1 - mean) * rs * g[c0 + 1] + be[c0 + 1];
  if (WF) {
    *(float2*)(outf + (size_t)row * CC + c0) = make_float2(o0, o1);
  } else {
    outb[(size_t)row * CC + c0] = (bf16_t)o0;
    outb[(size_t)row * CC + c0 + 1] = (bf16_t)o1;
  }
}

// gate+mix+LN+relu+residual; bf16 inputs (gpre, xc|ef), f32 x residual; bf16 out
__global__ __launch_bounds__(256) void ln_gate_kernel(
    const bf16_t* __restrict__ gpreb, const float* __restrict__ gate_b,
    const bf16_t* __restrict__ xcef, const float* __restrict__ n1g,
    const float* __restrict__ n1b, const float* __restrict__ xin,
    bf16_t* __restrict__ x2b) {
  int row = blockIdx.x, tid = threadIdx.x, c0 = tid * 2;
  __shared__ float red[8];
  float2 gp = ldb2(gpreb + (size_t)row * CC + c0);
  float2 xcv = ldb2(xcef + (size_t)row * (2 * CC) + c0);
  float2 efv = ldb2(xcef + (size_t)row * (2 * CC) + CC + c0);
  float g0 = 1.f / (1.f + __expf(-(gp.x + gate_b[c0])));
  float g1 = 1.f / (1.f + __expf(-(gp.y + gate_b[c0 + 1])));
  float x0 = g0 * xcv.x + (1.f - g0) * efv.x;
  float x1 = g1 * xcv.y + (1.f - g1) * efv.y;
  float s = x0 + x1, q = x0 * x0 + x1 * x1;
  block_reduce2(s, q, red);
  float mean = s * (1.f / CC);
  float var = q * (1.f / CC) - mean * mean;
  float rs = rsqrtf(var + 1e-5f);
  float2 xi = *(const float2*)(xin + (size_t)row * CC + c0);
  float o0 = fmaxf((x0 - mean) * rs * n1g[c0] + n1b[c0], 0.f) + xi.x;
  float o1 = fmaxf((x1 - mean) * rs * n1g[c0 + 1] + n1b[c0 + 1], 0.f) + xi.y;
  x2b[(size_t)row * CC + c0] = (bf16_t)o0;
  x2b[(size_t)row * CC + c0 + 1] = (bf16_t)o1;
}

// ---------------- V^T pack (pre-swizzled + pi-permuted K for attn) ---------
__global__ __launch_bounds__(256) void vt_pack_kernel(const bf16_t* __restrict__ qkvb,
                                                      bf16_t* __restrict__ vt) {
  int b = blockIdx.x >> 3, h = blockIdx.x & 7;
  int nb = b * 256;
  size_t voff = 1024 + (size_t)h * 64;
  char* out = (char*)(vt + (size_t)blockIdx.x * (64 * 256));
  __shared__ bf16_t tile[64][80];
  int tid = threadIdx.x;
  for (int kb = 0; kb < 4; ++kb) {
    __syncthreads();
#pragma unroll
    for (int p = 0; p < 2; ++p) {
      int k = p * 32 + (tid >> 3);
      int d8 = tid & 7;
      bf16x8 v = *(const bf16x8*)(qkvb + (size_t)(nb + kb * 64 + k) * 1536 + voff + d8 * 8);
      *(bf16x8*)(&tile[k][d8 * 8]) = v;
    }
    __syncthreads();
#pragma unroll
    for (int p = 0; p < 2; ++p) {
      int d = p * 32 + (tid >> 3);
      int k8 = tid & 7;
      bf16x8 v;
#pragma unroll
      for (int j = 0; j < 8; ++j) {
        int pos = k8 * 8 + j;
        int sl = pos & 31;
        int srck = (pos & 32) + ((sl >> 3) << 2) + (sl & 3) + (((sl >> 2) & 1) << 4);
        v[j] = tile[srck][d];
      }
      int byteoff = d * 512 + ((kb * 128 + k8 * 16) ^ ((d & 7) << 4));
      *(bf16x8*)(out + byteoff) = v;
    }
  }
}

// ---------------- MFMA attention (shuffle-free PV, setprio) ----------------
__global__ __launch_bounds__(256, 2) void attn_mfma_kernel(
    const bf16_t* __restrict__ qkvb, const bf16_t* __restrict__ vt,
    bf16_t* __restrict__ o) {
  const int b = blockIdx.x >> 3;
  const int h = blockIdx.x & 7;
  const int nb = b * 256;
  const int tid = threadIdx.x;
  const int lane = tid & 63;
  const int wv = tid >> 6;
  const int l15 = lane & 15;
  const int g = lane >> 4;
  const int swzk = (l15 & 7) << 4;
  __shared__ __align__(16) bf16_t Klds[256 * 64];
  __shared__ __align__(16) bf16_t Vtlds[64 * 256];
  const size_t qoff = (size_t)h * 64;
  const size_t koff = 512 + (size_t)h * 64;

  {
    const int dcol = 16 * ((tid & 7) ^ ((tid >> 3) & 7));
    const bf16_t* srcb = qkvb + koff + (dcol >> 1);
#pragma unroll
    for (int i = 0; i < 8; ++i) {
      int k = i * 32 + (tid >> 3);
      gl_lds16(srcb + (size_t)(nb + k) * 1536, Klds + ((i * 4096 + wv * 1024) >> 1));
    }
  }
  {
    const bf16_t* vsrc = vt + (size_t)blockIdx.x * (64 * 256);
#pragma unroll
    for (int i = 0; i < 8; ++i) {
      int base = i * 4096 + wv * 1024;
      gl_lds16(vsrc + ((base >> 1) + lane * 8), Vtlds + (base >> 1));
    }
  }

  bf16x8 qf[4][2];
#pragma unroll
  for (int n = 0; n < 4; ++n) {
    const bf16_t* qp = qkvb + (size_t)(nb + wv * 64 + 16 * n + l15) * 1536 + qoff + g * 8;
    qf[n][0] = *(const bf16x8*)(qp);
    qf[n][1] = *(const bf16x8*)(qp + 32);
  }

  __syncthreads();

  f32x4v oacc[4][4] = {};
  float mrun[4] = {-1e30f, -1e30f, -1e30f, -1e30f};
  float lrun[4] = {0.f, 0.f, 0.f, 0.f};

  for (int kc = 0; kc < 4; ++kc) {
    f32x4v sacc[4][4] = {};
    const int kb128 = (kc * 64 + l15) * 128;
    __builtin_amdgcn_s_setprio(1);
#pragma unroll
    for (int m = 0; m < 4; ++m) {
      bf16x8 a0 = *(const bf16x8*)(Klds + ((kb128 + m * 2048 + ((g * 16) ^ swzk)) >> 1));
      bf16x8 a1 =
          *(const bf16x8*)(Klds + ((kb128 + m * 2048 + ((64 + g * 16) ^ swzk)) >> 1));
#pragma unroll
      for (int n = 0; n < 4; ++n) {
        sacc[m][n] = __builtin_amdgcn_mfma_f32_16x16x32_bf16(a0, qf[n][0], sacc[m][n], 0, 0, 0);
        sacc[m][n] = __builtin_amdgcn_mfma_f32_16x16x32_bf16(a1, qf[n][1], sacc[m][n], 0, 0, 0);
      }
    }
    __builtin_amdgcn_s_setprio(0);
    uint2 pb[4][4];
#pragma unroll
    for (int n = 0; n < 4; ++n) {
      float mx = sacc[0][n][0];
#pragma unroll
      for (int m = 0; m < 4; ++m)
#pragma unroll
        for (int r = 0; r < 4; ++r) mx = fmaxf(mx, sacc[m][n][r]);
      mx = fmaxf(mx, __shfl_xor(mx, 16));
      mx = fmaxf(mx, __shfl_xor(mx, 32));
      float mnew = fmaxf(mrun[n], mx);
      float c = __expf((mrun[n] - mnew) * 0.125f);
      mrun[n] = mnew;
      float s = 0.f;
#pragma unroll
      for (int m = 0; m < 4; ++m) {
        float p0 = __expf((sacc[m][n][0] - mnew) * 0.125f);
        float p1 = __expf((sacc[m][n][1] - mnew) * 0.125f);
        float p2 = __expf((sacc[m][n][2] - mnew) * 0.125f);
        float p3 = __expf((sacc[m][n][3] - mnew) * 0.125f);
        s += (p0 + p1) + (p2 + p3);
        union { bf16x4 v; uint2 u; } cv;
        cv.v[0] = (bf16_t)p0; cv.v[1] = (bf16_t)p1;
        cv.v[2] = (bf16_t)p2; cv.v[3] = (bf16_t)p3;
        pb[m][n] = cv.u;
      }
      s += __shfl_xor(s, 16);
      s += __shfl_xor(s, 32);
      lrun[n] = lrun[n] * c + s;
#pragma unroll
      for (int m = 0; m < 4; ++m)
#pragma unroll
        for (int r = 0; r < 4; ++r) oacc[m][n][r] *= c;
    }
    __builtin_amdgcn_s_setprio(1);
#pragma unroll
    for (int h2 = 0; h2 < 2; ++h2) {
      bf16x8 vf[4];
#pragma unroll
      for (int m = 0; m < 4; ++m)
        vf[m] = *(const bf16x8*)(Vtlds + (((16 * m + l15) * 512 +
                                          ((kc * 128 + h2 * 64 + g * 16) ^ swzk)) >> 1));
#pragma unroll
      for (int n = 0; n < 4; ++n) {
        union { uint2 u[2]; bf16x8 v; } pf;
        pf.u[0] = pb[2 * h2][n];
        pf.u[1] = pb[2 * h2 + 1][n];
#pragma unroll
        for (int m = 0; m < 4; ++m)
          oacc[m][n] =
              __builtin_amdgcn_mfma_f32_16x16x32_bf16(vf[m], pf.v, oacc[m][n], 0, 0, 0);
      }
    }
    __builtin_amdgcn_s_setprio(0);
  }
  float inv[4];
#pragma unroll
  for (int n = 0; n < 4; ++n) inv[n] = 1.0f / lrun[n];
#pragma unroll
  for (int m = 0; m < 4; ++m)
#pragma unroll
    for (int n = 0; n < 4; ++n) {
      bf16x4 pk;
#pragma unroll
      for (int r = 0; r < 4; ++r) pk[r] = (bf16_t)(oacc[m][n][r] * inv[n]);
      *(bf16x4*)(o + (size_t)(nb + wv * 64 + 16 * n + l15) * 512 + h * 64 + 16 * m +
                 4 * g) = pk;
    }
}

// ---------------- launch ----------------

static inline char* alignp(char* p, size_t a) {
  return (char*)(((uintptr_t)p + a - 1) & ~(uintptr_t)(a - 1));
}

extern "C" void kernel_launch(void* const* d_in, const int* in_sizes, int n_in,
                              void* d_out, int out_size, void* d_ws, size_t ws_size,
                              hipStream_t stream) {
  const float* x = (const float*)d_in[0];
  const float* edge_attr = (const float*)d_in[1];
  const float* gcn_w = (const float*)d_in[2];
  const float* gcn_b = (const float*)d_in[3];
  const float* ep_w = (const float*)d_in[4];
  const float* ep_b = (const float*)d_in[5];
  const float* gate_w = (const float*)d_in[6];
  const float* gate_b = (const float*)d_in[7];
  const float* n1_g = (const float*)d_in[8];
  const float* n1_b = (const float*)d_in[9];
  const float* in_w = (const float*)d_in[10];
  const float* in_b = (const float*)d_in[11];
  const float* out_w = (const float*)d_in[12];
  const float* out_b = (const float*)d_in[13];
  const float* tn_g = (const float*)d_in[14];
  const float* tn_b = (const float*)d_in[15];
  const float* m_w1 = (const float*)d_in[16];
  const float* m_b1 = (const float*)d_in[17];
  const float* m_w2 = (const float*)d_in[18];
  const float* m_b2 = (const float*)d_in[19];
  const float* fn_g = (const float*)d_in[20];
  const float* fn_b = (const float*)d_in[21];
  const int* eidx = (const int*)d_in[22];
  const int* src = eidx;
  const int* dst = eidx + EE;

  float* ws = (float*)d_ws;
  float* R1 = ws;
  float* R2 = R1 + (size_t)NN * 3 * CC;
  float* R3 = R2 + (size_t)NN * CC;
  float* R4 = R3 + (size_t)NN * CC;
  float* dinv = R4 + (size_t)NN * CC;
  int* ip = (int*)(dinv + NN);
  int* ghist = ip;      ip += 64;
  int* gstart = ip;     ip += 65;
  int* gcur = ip;       ip += 64;
  int* elist_src = ip;  ip += EE;
  int* nid_src = ip;    ip += EE + 32;
  int* start_src = ip;  ip += NN + 1;
  int* start_dst = ip;  ip += NN + 1;
  char* bp = alignp((char*)ip, 64);
  int2* grec = (int2*)bp;             bp += (size_t)EE * 8;
  float* ewg = (float*)bp;            bp += (size_t)EE * 4;
  float2* dstrec = (float2*)bp;       bp += (size_t)EE * 8;
  bf16_t* x2b = (bf16_t*)bp;          bp += (size_t)NN * CC * 2;
  bf16_t* gcn_wt = (bf16_t*)bp;       bp += (size_t)CC * CC * 2;
  bf16_t* gate_wt = (bf16_t*)bp;      bp += (size_t)CC * 2 * CC * 2;
  bf16_t* in_wt = (bf16_t*)bp;        bp += (size_t)3 * CC * CC * 2;
  bf16_t* out_wt = (bf16_t*)bp;       bp += (size_t)CC * CC * 2;
  bf16_t* m_w1t = (bf16_t*)bp;        bp += (size_t)2 * CC * CC * 2;
  bf16_t* m_w2t = (bf16_t*)bp;        bp += (size_t)CC * 2 * CC * 2;

  bf16_t* xb = (bf16_t*)R1;      // bf16(x)
  bf16_t* xcefb = (bf16_t*)R1;   // [x_conv | ef] bf16 N x 2C
  bf16_t* qkvb = (bf16_t*)R1;    // qkv bf16 N x 1536
  bf16_t* hb = (bf16_t*)R1;      // mlp hidden bf16 N x 2C
  bf16_t* eacsr = (bf16_t*)((char*)R1 + (size_t)64 * 1024 * 1024);  // 16.8MB
  bf16_t* xwT = (bf16_t*)R2;     // (x@gcn_w)^T bf16 [512][16384]
  bf16_t* gpreb = (bf16_t*)R2;   // gate pre-act bf16 (after xwT dead)
  bf16_t* ob = (bf16_t*)R2;      // attn out bf16 (first half of R2)
  bf16_t* vt = ob + (size_t)NN * CC;  // V^T packed (second half of R2)
  bf16_t* x3b = (bf16_t*)R2;     // bf16(x3) (after ob dead)
  bf16_t* AnFull = (bf16_t*)R3;  // dense adjacency bf16 [16384][256] (8MB)
  bf16_t* oprjb = (bf16_t*)R4;   // out-proj bf16
  float* yf = R4;                // mlp2 f32 out (after oprjb dead)

  // --- edge prep ---
  init_kernel<<<1, 256, 0, stream>>>(ghist, nid_src, eacsr);
  edge_pass1<<<EE / 256, 256, 0, stream>>>(dst, ghist);
  gexscan_kernel<<<1, 64, 0, stream>>>(ghist, gstart, gcur);
  graph_scatter_kernel<<<EE / 2048, 256, 0, stream>>>(src, dst, edge_attr, gcur,
                                                      grec, ewg);
  graph_sort2_kernel<<<128, 1024, 0, stream>>>(grec, ewg, gstart, elist_src, nid_src,
                                               start_src, dstrec, start_dst, dinv);
  ea_gather_kernel<<<(EE * 2 + 255) / 256, 256, 0, stream>>>(edge_attr, elist_src,
                                                             eacsr);
  an_build_kernel<<<128, 256, 0, stream>>>(dstrec, start_dst, dinv, AnFull);

  // --- weight transposes ---
  wt_kernel<<<dim3(CC / 32, CC / 32), 256, 0, stream>>>(gcn_w, gcn_wt, CC, CC);
  wt_kernel<<<dim3(CC / 32, 2 * CC / 32), 256, 0, stream>>>(gate_w, gate_wt, 2 * CC, CC);
  wt_kernel<<<dim3(3 * CC / 32, CC / 32), 256, 0, stream>>>(in_w, in_wt, CC, 3 * CC);
  wt_kernel<<<dim3(CC / 32, CC / 32), 256, 0, stream>>>(out_w, out_wt, CC, CC);
  wt_kernel<<<dim3(2 * CC / 32, CC / 32), 256, 0, stream>>>(m_w1, m_w1t, CC, 2 * CC);
  wt_kernel<<<dim3(CC / 32, 2 * CC / 32), 256, 0, stream>>>(m_w2, m_w2t, 2 * CC, CC);

  // --- GCN conv: xwT = (x @ gcn_w)^T via flipped GEMM, then dense An GEMM ---
  cvt_bf16_kernel<<<(NN * CC / 4 + 255) / 256, 256, 0, stream>>>(x, xb, NN * CC / 4);
  gemm_bf16_kernel<0, 1><<<dim3(NN / 128, CC / 128), 256, 0, stream>>>(
      gcn_wt, xb, nullptr, xwT, CC, NN, CC);
  an_gemm_kernel<<<dim3(CC / 128, NN / 128), 256, 0, stream>>>(AnFull, xwT, gcn_b,
                                                               xcefb);
  ef_mfma_kernel<<<NN / 16, 512, 0, stream>>>(eacsr, ep_w, ep_b, nid_src, start_src,
                                              xcefb);
  dim3 gA(CC / 128, NN / 128);
  gemm_bf16_kernel<0, 1><<<gA, 256, 0, stream>>>(xcefb, gate_wt, nullptr, gpreb, NN,
                                                 CC, 2 * CC);
  ln_gate_kernel<<<NN, 256, 0, stream>>>(gpreb, gate_b, xcefb, n1_g, n1_b, x, x2b);

  // --- MHA ---
  dim3 gQ(3 * CC / 128, NN / 128);
  gemm_bf16_kernel<0, 1><<<gQ, 256, 0, stream>>>(x2b, in_wt, in_b, qkvb, NN, 3 * CC, CC);
  vt_pack_kernel<<<BB * HH, 256, 0, stream>>>(qkvb, vt);
  attn_mfma_kernel<<<BB * HH, 256, 0, stream>>>(qkvb, vt, ob);
  gemm_bf16_kernel<0, 1><<<gA, 256, 0, stream>>>(ob, out_wt, out_b, oprjb, NN, CC, CC);
  ln_addT_kernel<1, 1, 0><<<NN, 256, 0, stream>>>(x2b, oprjb, tn_g, tn_b, nullptr, x3b);

  // --- MLP ---
  dim3 gH(2 * CC / 128, NN / 128);
  gemm_bf16_kernel<1, 1><<<gH, 256, 0, stream>>>(x3b, m_w1t, m_b1, hb, NN, 2 * CC, CC);
  gemm_bf16_kernel<0, 0><<<gA, 256, 0, stream>>>(hb, m_w2t, m_b2, yf, NN, CC, 2 * CC);
  ln_addT_kernel<1, 0, 1><<<NN, 256, 0, stream>>>(x3b, yf, fn_g, fn_b, (float*)d_out,
                                                  nullptr);
}

// Round 18
// 416.688 us; speedup vs baseline: 1.0754x; 1.0642x over previous
//
#include <hip/hip_runtime.h>

#define NN 16384
#define CC 512
#define EE 524288
#define BB 64
#define HH 8
#define EFD 16
#define GEMAXE 10240

typedef __bf16 bf16_t;
typedef __bf16 bf16x4 __attribute__((ext_vector_type(4)));
typedef __bf16 bf16x8 __attribute__((ext_vector_type(8)));
typedef float f32x4v __attribute__((ext_vector_type(4)));

__device__ __forceinline__ float2 ldb2(const bf16_t* p) {
  unsigned w = *(const unsigned*)p;
  return make_float2(__uint_as_float(w << 16), __uint_as_float(w & 0xFFFF0000u));
}

__device__ __forceinline__ float4 ldb4(const bf16_t* p) {
  uint2 w = *(const uint2*)p;
  return make_float4(__uint_as_float(w.x << 16), __uint_as_float(w.x & 0xFFFF0000u),
                     __uint_as_float(w.y << 16), __uint_as_float(w.y & 0xFFFF0000u));
}

// XCD-aware chunked swizzle (nwg % 8 == 0 for all our grids)
__device__ __forceinline__ int2 xcd_swizzle() {
  int nwg = gridDim.x * gridDim.y;
  int bid = blockIdx.y * gridDim.x + blockIdx.x;
  int wg = (bid & 7) * (nwg >> 3) + (bid >> 3);
  return make_int2(wg % gridDim.x, wg / gridDim.x);
}

// ---------------- init / edge pre-pass ----------------

__global__ void init_kernel(int* ghist, int* nid_src, bf16_t* eacsr) {
  int i = threadIdx.x;
  if (i < 64) ghist[i] = 0;
  if (i < 32) nid_src[EE + i] = -1;               // pad for ef chunk tail
  ((int*)(eacsr + (size_t)EE * 16))[i] = 0;       // zero eacsr pad rows (256 ints)
}

// per-graph histogram only (LDS-aggregated)
__global__ __launch_bounds__(256) void edge_pass1(const int* __restrict__ dst,
                                                  int* ghist) {
  __shared__ int h[64];
  int tid = threadIdx.x;
  if (tid < 64) h[tid] = 0;
  __syncthreads();
  int e = blockIdx.x * 256 + tid;  // EE % 256 == 0
  atomicAdd(&h[dst[e] >> 8], 1);
  __syncthreads();
  if (tid < 64 && h[tid]) atomicAdd(&ghist[tid], h[tid]);
}

__global__ void gexscan_kernel(const int* __restrict__ ghist, int* __restrict__ gstart,
                               int* __restrict__ gcur) {
  if (threadIdx.x == 0) {
    int s = 0;
    for (int g = 0; g < 64; ++g) { gstart[g] = s; gcur[g] = s; s += ghist[g]; }
    gstart[64] = s;
  }
}

// bucket edges by graph with block-aggregated offsets; emit packed records.
// ew computed inline from ea (single pass over edge_attr).
__global__ __launch_bounds__(256) void graph_scatter_kernel(
    const int* __restrict__ src, const int* __restrict__ dst,
    const float* __restrict__ ea, int* gcur, int2* __restrict__ grec,
    float* __restrict__ ewg) {
  __shared__ int h[64], base[64], h2[64];
  int tid = threadIdx.x;
  if (tid < 64) { h[tid] = 0; h2[tid] = 0; }
  __syncthreads();
  int e0 = blockIdx.x * 2048;
  int gloc[8];
#pragma unroll
  for (int k = 0; k < 8; ++k) {
    gloc[k] = dst[e0 + k * 256 + tid] >> 8;
    atomicAdd(&h[gloc[k]], 1);
  }
  __syncthreads();
  if (tid < 64) base[tid] = h[tid] ? atomicAdd(&gcur[tid], h[tid]) : 0;
  __syncthreads();
#pragma unroll
  for (int k = 0; k < 8; ++k) {
    int e = e0 + k * 256 + tid;
    int g = gloc[k];
    int p = atomicAdd(&h2[g], 1);
    int pos = base[g] + p;
    int ls = src[e] & 255;
    int ld = dst[e] & 255;
    grec[pos] = make_int2(e | (ls << 19), ld);
    const float4* pa = (const float4*)(ea + (size_t)e * EFD);
    float s = 0.f;
#pragma unroll
    for (int q = 0; q < 4; ++q) {
      float4 v = pa[q];
      s += v.x * v.x + v.y * v.y + v.z * v.z + v.w * v.w;
    }
    ewg[pos] = sqrtf(s);
  }
}

// per-graph LDS counting sort, 128 blocks: blockIdx<64 -> DST pass, else SRC.
__global__ __launch_bounds__(1024) void graph_sort2_kernel(
    const int2* __restrict__ grec, const float* __restrict__ ewg,
    const int* __restrict__ gstart, int* __restrict__ elist_src,
    int* __restrict__ nid_src, int* __restrict__ start_src,
    float2* __restrict__ dstrec, int* __restrict__ start_dst,
    float* __restrict__ dinv) {
  __shared__ int lbuf[GEMAXE];
  __shared__ unsigned short sl[GEMAXE];
  __shared__ float ewl[GEMAXE];
  __shared__ int h[256], hx[256], h2[256];
  __shared__ float fdinv[256];
  const int g = blockIdx.x & 63;
  const int tid = threadIdx.x;
  const int gs = gstart[g];
  const int cnt = gstart[g + 1] - gs;
  if (tid < 256) { h[tid] = 0; h2[tid] = 0; }
  __syncthreads();
  if (blockIdx.x < 64) {
    for (int i = tid; i < cnt; i += 1024) {
      int2 r = grec[gs + i];
      int ld = r.y;
      sl[i] = (unsigned short)(((r.x >> 19) & 255) | (ld << 8));
      ewl[i] = ewg[gs + i];
      atomicAdd(&h[ld], 1);
    }
    __syncthreads();
    int myc = (tid < 256) ? h[tid] : 0;
    for (int off = 1; off < 256; off <<= 1) {
      int v = (tid < 256 && tid >= off) ? h[tid - off] : 0;
      __syncthreads();
      if (tid < 256) h[tid] += v;
      __syncthreads();
    }
    if (tid < 256) {
      hx[tid] = h[tid] - myc;
      start_dst[g * 256 + tid] = gs + hx[tid];
    }
    if (g == 63 && tid == 0) start_dst[NN] = EE;
    __syncthreads();
    for (int i = tid; i < cnt; i += 1024) {
      int ld = sl[i] >> 8;
      int p = hx[ld] + atomicAdd(&h2[ld], 1);
      lbuf[p] = i;
    }
    __syncthreads();
    if (tid < 256) {
      float dg = 1.0f;
      int s0 = hx[tid], e0 = s0 + myc;
      for (int i = s0; i < e0; ++i) dg += ewl[lbuf[i]];
      float dv = rsqrtf(fmaxf(dg, 1e-12f));
      fdinv[tid] = dv;
      dinv[g * 256 + tid] = dv;
    }
    __syncthreads();
    for (int p = tid; p < cnt; p += 1024) {
      int i = lbuf[p];
      int ls = sl[i] & 255;
      int ld = sl[i] >> 8;
      dstrec[gs + p] =
          make_float2(fdinv[ls] * ewl[i] * fdinv[ld], __int_as_float(ls));
    }
  } else {
    int* wb = (int*)ewl;
    for (int i = tid; i < cnt; i += 1024) {
      int w = grec[gs + i].x;
      wb[i] = w;
      atomicAdd(&h[w >> 19], 1);
    }
    __syncthreads();
    int myc = (tid < 256) ? h[tid] : 0;
    for (int off = 1; off < 256; off <<= 1) {
      int v = (tid < 256 && tid >= off) ? h[tid - off] : 0;
      __syncthreads();
      if (tid < 256) h[tid] += v;
      __syncthreads();
    }
    if (tid < 256) {
      hx[tid] = h[tid] - myc;
      start_src[g * 256 + tid] = gs + hx[tid];
    }
    if (g == 63 && tid == 0) start_src[NN] = EE;
    __syncthreads();
    for (int i = tid; i < cnt; i += 1024) {
      int w = wb[i];
      int ls = w >> 19;
      int p = hx[ls] + atomicAdd(&h2[ls], 1);
      lbuf[p] = w;
    }
    __syncthreads();
    for (int p = tid; p < cnt; p += 1024) {
      int w = lbuf[p];
      elist_src[gs + p] = w & 0x7FFFF;
      nid_src[gs + p] = g * 256 + (w >> 19);
    }
  }
}

// gather edge_attr rows into CSR order as bf16
__global__ void ea_gather_kernel(const float* __restrict__ ea,
                                 const int* __restrict__ elist,
                                 bf16_t* __restrict__ eacsr) {
  int idx = blockIdx.x * 256 + threadIdx.x;
  if (idx >= EE * 2) return;
  int pos = idx >> 1, half = idx & 1;
  int e = elist[pos];
  const f32x4v* p = (const f32x4v*)(ea + (size_t)e * EFD + half * 8);
  f32x4v u0 = p[0], u1 = p[1];
  bf16x8 f;
#pragma unroll
  for (int r = 0; r < 4; ++r) {
    f[r] = (bf16_t)u0[r];
    f[4 + r] = (bf16_t)u1[r];
  }
  *(bf16x8*)(eacsr + (size_t)pos * 16 + half * 8) = f;
}

// ---------------- dense per-graph adjacency build ----------------
__global__ __launch_bounds__(256) void an_build_kernel(
    const float2* __restrict__ dstrec, const int* __restrict__ start_dst,
    const float* __restrict__ dinv, bf16_t* __restrict__ An) {
  __shared__ float AnS[128][256];  // 128 KB
  const int g = blockIdx.x >> 1, h = blockIdx.x & 1;
  const int tid = threadIdx.x;
  float4* az = (float4*)&AnS[0][0];
  for (int i = tid; i < 128 * 256 / 4; i += 256)
    az[i] = make_float4(0.f, 0.f, 0.f, 0.f);
  __syncthreads();
  const int nbase = g * 256 + h * 128;
  if (tid < 128) {
    int node = nbase + tid;
    int st = start_dst[node], en = start_dst[node + 1];
    float* row = AnS[tid];
    for (int p = st; p < en; ++p) {
      float2 r = dstrec[p];
      row[__float_as_int(r.y)] += r.x;
    }
    float dv = dinv[node];
    row[h * 128 + tid] += dv * dv;
  }
  __syncthreads();
  bf16_t* out = An + (size_t)nbase * 256;
  const float* s0 = &AnS[0][0];
  for (int i = tid; i < 128 * 256 / 8; i += 256) {
    bf16x8 v;
#pragma unroll
    for (int r = 0; r < 8; ++r) v[r] = (bf16_t)s0[i * 8 + r];
    *(bf16x8*)(out + i * 8) = v;
  }
}

// ---------------- conversions ----------------

__global__ void cvt_bf16_kernel(const float* __restrict__ in, bf16_t* __restrict__ out,
                                int n4) {
  int i = blockIdx.x * 256 + threadIdx.x;
  if (i >= n4) return;
  float4 v = ((const float4*)in)[i];
  bf16x4 o;
  o[0] = (bf16_t)v.x; o[1] = (bf16_t)v.y; o[2] = (bf16_t)v.z; o[3] = (bf16_t)v.w;
  ((bf16x4*)out)[i] = o;
}

// W: f32 [K][N] row-major -> Wt: bf16 [N][K] row-major
__global__ __launch_bounds__(256) void wt_kernel(const float* __restrict__ W,
                                                 bf16_t* __restrict__ Wt, int K, int N) {
  __shared__ float tile[32][33];
  int bx = blockIdx.x * 32;
  int by = blockIdx.y * 32;
  int tx = threadIdx.x & 31, ty = threadIdx.x >> 5;
#pragma unroll
  for (int i = 0; i < 32; i += 8)
    tile[ty + i][tx] = W[(size_t)(by + ty + i) * N + bx + tx];
  __syncthreads();
#pragma unroll
  for (int i = 0; i < 32; i += 8)
    Wt[(size_t)(bx + ty + i) * K + by + tx] = (bf16_t)tile[tx][ty + i];
}

// ---------------- edge projection via double-MFMA (8 waves x 64 cols) ------
__global__ __launch_bounds__(512) void ef_mfma_kernel(
    const bf16_t* __restrict__ eacsr, const float* __restrict__ ep_w,
    const float* __restrict__ ep_b, const int* __restrict__ nid,
    const int* __restrict__ start, bf16_t* __restrict__ efb) {
  const int tid = threadIdx.x;
  const int lane = tid & 63;
  const int wv = tid >> 6;      // 0..7
  const int l15 = lane & 15;
  const int g = lane >> 4;
  const int n0 = blockIdx.x * 16;
  const int cbase = wv * 64;

  bf16x8 wfr[4];
#pragma unroll
  for (int t = 0; t < 4; ++t) {
    bf16x8 f = {};
    int c = cbase + t * 16 + l15;
    if (g < 2) {
#pragma unroll
      for (int j = 0; j < 8; ++j) f[j] = (bf16_t)ep_w[(g * 8 + j) * CC + c];
    } else if (g == 2) {
      f[0] = (bf16_t)ep_b[c];
    }
    wfr[t] = f;
  }

  const int st = start[n0];
  const int en = start[n0 + 16];
  const int tgt = n0 + l15;

  f32x4v eacc[4] = {};

  for (int cb = st; cb < en; cb += 32) {
    bf16x8 af[2];
#pragma unroll
    for (int mE = 0; mE < 2; ++mE) {
      bf16x8 f = {};
      if (g < 2) {
        f = *(const bf16x8*)(eacsr + (size_t)(cb + mE * 16 + l15) * 16 + g * 8);
      } else if (g == 2) {
        f[0] = (bf16_t)1.0f;
      }
      af[mE] = f;
    }
    int4 idlo = *(const int4*)(nid + cb + g * 4);
    int4 idhi = *(const int4*)(nid + cb + 16 + g * 4);
    bf16x8 sf;
    sf[0] = (idlo.x == tgt) ? (bf16_t)1.0f : (bf16_t)0.0f;
    sf[1] = (idlo.y == tgt) ? (bf16_t)1.0f : (bf16_t)0.0f;
    sf[2] = (idlo.z == tgt) ? (bf16_t)1.0f : (bf16_t)0.0f;
    sf[3] = (idlo.w == tgt) ? (bf16_t)1.0f : (bf16_t)0.0f;
    sf[4] = (idhi.x == tgt) ? (bf16_t)1.0f : (bf16_t)0.0f;
    sf[5] = (idhi.y == tgt) ? (bf16_t)1.0f : (bf16_t)0.0f;
    sf[6] = (idhi.z == tgt) ? (bf16_t)1.0f : (bf16_t)0.0f;
    sf[7] = (idhi.w == tgt) ? (bf16_t)1.0f : (bf16_t)0.0f;
    __builtin_amdgcn_s_setprio(1);
#pragma unroll
    for (int t = 0; t < 4; ++t) {
      f32x4v s0 = {}, s1 = {};
      s0 = __builtin_amdgcn_mfma_f32_16x16x32_bf16(af[0], wfr[t], s0, 0, 0, 0);
      s1 = __builtin_amdgcn_mfma_f32_16x16x32_bf16(af[1], wfr[t], s1, 0, 0, 0);
      union { bf16x8 v; bf16x4 h[2]; } pf;
#pragma unroll
      for (int r = 0; r < 4; ++r) {
        pf.h[0][r] = (bf16_t)fmaxf(s0[r], 0.f);
        pf.h[1][r] = (bf16_t)fmaxf(s1[r], 0.f);
      }
      eacc[t] = __builtin_amdgcn_mfma_f32_16x16x32_bf16(sf, pf.v, eacc[t], 0, 0, 0);
    }
    __builtin_amdgcn_s_setprio(0);
  }
#pragma unroll
  for (int t = 0; t < 4; ++t) {
    int c = cbase + t * 16 + l15;
#pragma unroll
    for (int r = 0; r < 4; ++r) {
      int node = n0 + g * 4 + r;
      efb[(size_t)node * (2 * CC) + CC + c] = (bf16_t)eacc[t][r];
    }
  }
}

// ---------------- bf16 MFMA GEMM: BK=64, swizzled LDS, XCD, 8 waves --------
__device__ __forceinline__ void gl_lds16(const bf16_t* g, bf16_t* l) {
  __builtin_amdgcn_global_load_lds(
      (const __attribute__((address_space(1))) void*)g,
      (__attribute__((address_space(3))) void*)l, 16, 0, 0);
}

// 128x128 tile, 512 threads (8 waves as 4Mx2N, per-wave 32x64 out).
// LDS [128][64] bf16; slot sl of row r holds global k-slot sl^(r&7).
// Stage: linear dest (tid*8), pre-swizzled global source. 2-lane/bank reads.
template <int ACT, int OUT>
__global__ __launch_bounds__(512) void gemm_bf16_kernel(
    const bf16_t* __restrict__ A, const bf16_t* __restrict__ Bt,
    const float* __restrict__ bias, void* __restrict__ Cout, int M, int N, int K) {
  __shared__ __align__(16) bf16_t Al[128 * 64];
  __shared__ __align__(16) bf16_t Bl[128 * 64];
  const int tid = threadIdx.x;
  const int lane = tid & 63;
  const int wave = tid >> 6;
  int2 sw = xcd_swizzle();
  const int row0 = sw.y * 128;
  const int col0 = sw.x * 128;
  const int wm = wave >> 1;   // 0..3 (32 rows each)
  const int wn = wave & 1;    // 0..1 (64 cols each)
  f32x4v acc[2][4] = {};
  // staging: thread t covers row (t>>3) [+64 for 2nd issue], slot (t&7)
  const int srow = tid >> 3;
  const int sslot = (tid & 7) ^ (srow & 7);
  const bf16_t* aBase = A + (size_t)(row0 + srow) * K + sslot * 8;
  const bf16_t* bBase = Bt + (size_t)(col0 + srow) * K + sslot * 8;
  const int fr = lane & 15;
  const int g = lane >> 4;
  const int f7 = fr & 7;
  for (int k0 = 0; k0 < K; k0 += 64) {
    gl_lds16(aBase + k0, Al + tid * 8);
    gl_lds16(aBase + (size_t)64 * K + k0, Al + 4096 + tid * 8);
    gl_lds16(bBase + k0, Bl + tid * 8);
    gl_lds16(bBase + (size_t)64 * K + k0, Bl + 4096 + tid * 8);
    __syncthreads();
#pragma unroll
    for (int s = 0; s < 2; ++s) {
      const int sl = ((s * 4 + g) ^ f7) * 8;
      bf16x8 af[2], bfv[4];
#pragma unroll
      for (int m = 0; m < 2; ++m)
        af[m] = *(const bf16x8*)(Al + (wm * 32 + m * 16 + fr) * 64 + sl);
#pragma unroll
      for (int n = 0; n < 4; ++n)
        bfv[n] = *(const bf16x8*)(Bl + (wn * 64 + n * 16 + fr) * 64 + sl);
#pragma unroll
      for (int m = 0; m < 2; ++m)
#pragma unroll
        for (int n = 0; n < 4; ++n)
          acc[m][n] = __builtin_amdgcn_mfma_f32_16x16x32_bf16(af[m], bfv[n],
                                                              acc[m][n], 0, 0, 0);
    }
    __syncthreads();
  }
  const int fq = (lane >> 4) * 4;
#pragma unroll
  for (int m = 0; m < 2; ++m) {
    int grb = row0 + wm * 32 + m * 16 + fq;
#pragma unroll
    for (int n = 0; n < 4; ++n) {
      int gc = col0 + wn * 64 + n * 16 + fr;
      float bv = bias ? bias[gc] : 0.f;
#pragma unroll
      for (int r = 0; r < 4; ++r) {
        float v = acc[m][n][r] + bv;
        if (ACT == 1) v = v / (1.f + __expf(-v));
        if (OUT == 0)
          ((float*)Cout)[(size_t)(grb + r) * N + gc] = v;
        else
          ((bf16_t*)Cout)[(size_t)(grb + r) * N + gc] = (bf16_t)v;
      }
    }
  }
}

// ---------------- block-diagonal An GEMM (BK=64, swizzled, 8 waves) --------
__global__ __launch_bounds__(512) void an_gemm_kernel(
    const bf16_t* __restrict__ An, const bf16_t* __restrict__ xwT,
    const float* __restrict__ bias, bf16_t* __restrict__ outb) {
  __shared__ __align__(16) bf16_t Al[128 * 64];
  __shared__ __align__(16) bf16_t Bl[128 * 64];
  const int tid = threadIdx.x;
  const int lane = tid & 63;
  const int wave = tid >> 6;
  int2 sw = xcd_swizzle();
  const int row0 = sw.y * 128;  // node rows
  const int col0 = sw.x * 128;  // chan cols
  const int gr = row0 >> 8;     // graph
  const int wm = wave >> 1;
  const int wn = wave & 1;
  f32x4v acc[2][4] = {};
  const int srow = tid >> 3;
  const int sslot = (tid & 7) ^ (srow & 7);
  const bf16_t* aBase = An + (size_t)(row0 + srow) * 256 + sslot * 8;
  const bf16_t* bBase = xwT + (size_t)(col0 + srow) * NN + gr * 256 + sslot * 8;
  const int fr = lane & 15;
  const int g = lane >> 4;
  const int f7 = fr & 7;
  for (int k0 = 0; k0 < 256; k0 += 64) {
    gl_lds16(aBase + k0, Al + tid * 8);
    gl_lds16(aBase + (size_t)64 * 256 + k0, Al + 4096 + tid * 8);
    gl_lds16(bBase + k0, Bl + tid * 8);
    gl_lds16(bBase + (size_t)64 * NN + k0, Bl + 4096 + tid * 8);
    __syncthreads();
#pragma unroll
    for (int s = 0; s < 2; ++s) {
      const int sl = ((s * 4 + g) ^ f7) * 8;
      bf16x8 af[2], bfv[4];
#pragma unroll
      for (int m = 0; m < 2; ++m)
        af[m] = *(const bf16x8*)(Al + (wm * 32 + m * 16 + fr) * 64 + sl);
#pragma unroll
      for (int n = 0; n < 4; ++n)
        bfv[n] = *(const bf16x8*)(Bl + (wn * 64 + n * 16 + fr) * 64 + sl);
#pragma unroll
      for (int m = 0; m < 2; ++m)
#pragma unroll
        for (int n = 0; n < 4; ++n)
          acc[m][n] = __builtin_amdgcn_mfma_f32_16x16x32_bf16(af[m], bfv[n],
                                                              acc[m][n], 0, 0, 0);
    }
    __syncthreads();
  }
  const int fq = (lane >> 4) * 4;
#pragma unroll
  for (int m = 0; m < 2; ++m) {
    int grb = row0 + wm * 32 + m * 16 + fq;
#pragma unroll
    for (int n = 0; n < 4; ++n) {
      int gc = col0 + wn * 64 + n * 16 + fr;
      float bv = bias[gc];
#pragma unroll
      for (int r = 0; r < 4; ++r)
        outb[(size_t)(grb + r) * (2 * CC) + gc] = (bf16_t)(acc[m][n][r] + bv);
    }
  }
}

// ---------------- layernorm fused kernels (128 thr/row, float4) ------------

__device__ inline void block_reduce2_2w(float& s, float& q, float* red) {
#pragma unroll
  for (int off = 32; off >= 1; off >>= 1) {
    s += __shfl_xor(s, off, 64);
    q += __shfl_xor(q, off, 64);
  }
  int wid = threadIdx.x >> 6;
  if ((threadIdx.x & 63) == 0) { red[wid * 2] = s; red[wid * 2 + 1] = q; }
  __syncthreads();
  s = red[0] + red[2];
  q = red[1] + red[3];
}

// out = LN(A + B) * g + be ; IA/IB: 1 = bf16 input; WF: 1 = f32 out, else bf16
template <int IA, int IB, int WF>
__global__ __launch_bounds__(128) void ln_addT_kernel(
    const void* __restrict__ A, const void* __restrict__ Bv,
    const float* __restrict__ g, const float* __restrict__ be,
    float* __restrict__ outf, bf16_t* __restrict__ outb) {
  int row = blockIdx.x, tid = threadIdx.x, c0 = tid * 4;
  __shared__ float red[4];
  float4 a = IA ? ldb4((const bf16_t*)A + (size_t)row * CC + c0)
                : *(const float4*)((const float*)A + (size_t)row * CC + c0);
  float4 b = IB ? ldb4((const bf16_t*)Bv + (size_t)row * CC + c0)
                : *(const float4*)((const float*)Bv + (size_t)row * CC + c0);
  float x0 = a.x + b.x, x1 = a.y + b.y, x2 = a.z + b.z, x3 = a.w + b.w;
  float s = (x0 + x1) + (x2 + x3);
  float q = (x0 * x0 + x1 * x1) + (x2 * x2 + x3 * x3);
  block_reduce2_2w(s, q, red);
  float mean = s * (1.f / CC);
  float var = q * (1.f / CC) - mean * mean;
  float rs = rsqrtf(var + 1e-5f);
  float4 gg = *(const float4*)(g + c0);
  float4 bb = *(const float4*)(be + c0);
  float o0 = (x0 - mean) * rs * gg.x + bb.x;
  float o1 = (x1 - mean) * rs * gg.y + bb.y;
  float o2 = (x2 - mean) * rs * gg.z + bb.z;
  float o3 = (x3 - mean) * rs * gg.w + bb.w;
  if (WF) {
    *(float4*)(outf + (size_t)row * CC + c0) = make_float4(o0, o1, o2, o3);
  } else {
    bf16x4 pk;
    pk[0] = (bf16_t)o0; pk[1] = (bf16_t)o1; pk[2] = (bf16_t)o2; pk[3] = (bf16_t)o3;
    *(bf16x4*)(outb + (size_t)row * CC + c0) = pk;
  }
}

// gate+mix+LN+relu+residual; bf16 inputs (gpre, xc|ef), f32 x residual; bf16 out
__global__ __launch_bounds__(128) void ln_gate_kernel(
    const bf16_t* __restrict__ gpreb, const float* __restrict__ gate_b,
    const bf16_t* __restrict__ xcef, const float* __restrict__ n1g,
    const float* __restrict__ n1b, const float* __restrict__ xin,
    bf16_t* __restrict__ x2b) {
  int row = blockIdx.x, tid = threadIdx.x, c0 = tid * 4;
  __shared__ float red[4];
  float4 gp = ldb4(gpreb + (size_t)row * CC + c0);
  float4 xcv = ldb4(xcef + (size_t)row * (2 * CC) + c0);
  float4 efv = ldb4(xcef + (size_t)row * (2 * CC) + CC + c0);
  float4 gb = *(const float4*)(gate_b + c0);
  float g0 = 1.f / (1.f + __expf(-(gp.x + gb.x)));
  float g1 = 1.f / (1.f + __expf(-(gp.y + gb.y)));
  float g2 = 1.f / (1.f + __expf(-(gp.z + gb.z)));
  float g3 = 1.f / (1.f + __expf(-(gp.w + gb.w)));
  float x0 = g0 * xcv.x + (1.f - g0) * efv.x;
  float x1 = g1 * xcv.y + (1.f - g1) * efv.y;
  float x2 = g2 * xcv.z + (1.f - g2) * efv.z;
  float x3 = g3 * xcv.w + (1.f - g3) * efv.w;
  float s = (x0 + x1) + (x2 + x3);
  float q = (x0 * x0 + x1 * x1) + (x2 * x2 + x3 * x3);
  block_reduce2_2w(s, q, red);
  float mean = s * (1.f / CC);
  float var = q * (1.f / CC) - mean * mean;
  float rs = rsqrtf(var + 1e-5f);
  float4 ng = *(const float4*)(n1g + c0);
  float4 nb = *(const float4*)(n1b + c0);
  float4 xi = *(const float4*)(xin + (size_t)row * CC + c0);
  float o0 = fmaxf((x0 - mean) * rs * ng.x + nb.x, 0.f) + xi.x;
  float o1 = fmaxf((x1 - mean) * rs * ng.y + nb.y, 0.f) + xi.y;
  float o2 = fmaxf((x2 - mean) * rs * ng.z + nb.z, 0.f) + xi.z;
  float o3 = fmaxf((x3 - mean) * rs * ng.w + nb.w, 0.f) + xi.w;
  bf16x4 pk;
  pk[0] = (bf16_t)o0; pk[1] = (bf16_t)o1; pk[2] = (bf16_t)o2; pk[3] = (bf16_t)o3;
  *(bf16x4*)(x2b + (size_t)row * CC + c0) = pk;
}

// ---------------- V^T pack (pre-swizzled + pi-permuted K for attn) ---------
__global__ __launch_bounds__(256) void vt_pack_kernel(const bf16_t* __restrict__ qkvb,
                                                      bf16_t* __restrict__ vt) {
  int b = blockIdx.x >> 3, h = blockIdx.x & 7;
  int nb = b * 256;
  size_t voff = 1024 + (size_t)h * 64;
  char* out = (char*)(vt + (size_t)blockIdx.x * (64 * 256));
  __shared__ bf16_t tile[64][80];
  int tid = threadIdx.x;
  for (int kb = 0; kb < 4; ++kb) {
    __syncthreads();
#pragma unroll
    for (int p = 0; p < 2; ++p) {
      int k = p * 32 + (tid >> 3);
      int d8 = tid & 7;
      bf16x8 v = *(const bf16x8*)(qkvb + (size_t)(nb + kb * 64 + k) * 1536 + voff + d8 * 8);
      *(bf16x8*)(&tile[k][d8 * 8]) = v;
    }
    __syncthreads();
#pragma unroll
    for (int p = 0; p < 2; ++p) {
      int d = p * 32 + (tid >> 3);
      int k8 = tid & 7;
      bf16x8 v;
#pragma unroll
      for (int j = 0; j < 8; ++j) {
        int pos = k8 * 8 + j;
        int sl = pos & 31;
        int srck = (pos & 32) + ((sl >> 3) << 2) + (sl & 3) + (((sl >> 2) & 1) << 4);
        v[j] = tile[srck][d];
      }
      int byteoff = d * 512 + ((kb * 128 + k8 * 16) ^ ((d & 7) << 4));
      *(bf16x8*)(out + byteoff) = v;
    }
  }
}

// ---------------- MFMA attention (shuffle-free PV, setprio) ----------------
__global__ __launch_bounds__(256, 2) void attn_mfma_kernel(
    const bf16_t* __restrict__ qkvb, const bf16_t* __restrict__ vt,
    bf16_t* __restrict__ o) {
  const int b = blockIdx.x >> 3;
  const int h = blockIdx.x & 7;
  const int nb = b * 256;
  const int tid = threadIdx.x;
  const int lane = tid & 63;
  const int wv = tid >> 6;
  const int l15 = lane & 15;
  const int g = lane >> 4;
  const int swzk = (l15 & 7) << 4;
  __shared__ __align__(16) bf16_t Klds[256 * 64];
  __shared__ __align__(16) bf16_t Vtlds[64 * 256];
  const size_t qoff = (size_t)h * 64;
  const size_t koff = 512 + (size_t)h * 64;

  {
    const int dcol = 16 * ((tid & 7) ^ ((tid >> 3) & 7));
    const bf16_t* srcb = qkvb + koff + (dcol >> 1);
#pragma unroll
    for (int i = 0; i < 8; ++i) {
      int k = i * 32 + (tid >> 3);
      gl_lds16(srcb + (size_t)(nb + k) * 1536, Klds + ((i * 4096 + wv * 1024) >> 1));
    }
  }
  {
    const bf16_t* vsrc = vt + (size_t)blockIdx.x * (64 * 256);
#pragma unroll
    for (int i = 0; i < 8; ++i) {
      int base = i * 4096 + wv * 1024;
      gl_lds16(vsrc + ((base >> 1) + lane * 8), Vtlds + (base >> 1));
    }
  }

  bf16x8 qf[4][2];
#pragma unroll
  for (int n = 0; n < 4; ++n) {
    const bf16_t* qp = qkvb + (size_t)(nb + wv * 64 + 16 * n + l15) * 1536 + qoff + g * 8;
    qf[n][0] = *(const bf16x8*)(qp);
    qf[n][1] = *(const bf16x8*)(qp + 32);
  }

  __syncthreads();

  f32x4v oacc[4][4] = {};
  float mrun[4] = {-1e30f, -1e30f, -1e30f, -1e30f};
  float lrun[4] = {0.f, 0.f, 0.f, 0.f};

  for (int kc = 0; kc < 4; ++kc) {
    f32x4v sacc[4][4] = {};
    const int kb128 = (kc * 64 + l15) * 128;
    __builtin_amdgcn_s_setprio(1);
#pragma unroll
    for (int m = 0; m < 4; ++m) {
      bf16x8 a0 = *(const bf16x8*)(Klds + ((kb128 + m * 2048 + ((g * 16) ^ swzk)) >> 1));
      bf16x8 a1 =
          *(const bf16x8*)(Klds + ((kb128 + m * 2048 + ((64 + g * 16) ^ swzk)) >> 1));
#pragma unroll
      for (int n = 0; n < 4; ++n) {
        sacc[m][n] = __builtin_amdgcn_mfma_f32_16x16x32_bf16(a0, qf[n][0], sacc[m][n], 0, 0, 0);
        sacc[m][n] = __builtin_amdgcn_mfma_f32_16x16x32_bf16(a1, qf[n][1], sacc[m][n], 0, 0, 0);
      }
    }
    __builtin_amdgcn_s_setprio(0);
    uint2 pb[4][4];
#pragma unroll
    for (int n = 0; n < 4; ++n) {
      float mx = sacc[0][n][0];
#pragma unroll
      for (int m = 0; m < 4; ++m)
#pragma unroll
        for (int r = 0; r < 4; ++r) mx = fmaxf(mx, sacc[m][n][r]);
      mx = fmaxf(mx, __shfl_xor(mx, 16));
      mx = fmaxf(mx, __shfl_xor(mx, 32));
      float mnew = fmaxf(mrun[n], mx);
      float c = __expf((mrun[n] - mnew) * 0.125f);
      mrun[n] = mnew;
      float s = 0.f;
#pragma unroll
      for (int m = 0; m < 4; ++m) {
        float p0 = __expf((sacc[m][n][0] - mnew) * 0.125f);
        float p1 = __expf((sacc[m][n][1] - mnew) * 0.125f);
        float p2 = __expf((sacc[m][n][2] - mnew) * 0.125f);
        float p3 = __expf((sacc[m][n][3] - mnew) * 0.125f);
        s += (p0 + p1) + (p2 + p3);
        union { bf16x4 v; uint2 u; } cv;
        cv.v[0] = (bf16_t)p0; cv.v[1] = (bf16_t)p1;
        cv.v[2] = (bf16_t)p2; cv.v[3] = (bf16_t)p3;
        pb[m][n] = cv.u;
      }
      s += __shfl_xor(s, 16);
      s += __shfl_xor(s, 32);
      lrun[n] = lrun[n] * c + s;
#pragma unroll
      for (int m = 0; m < 4; ++m)
#pragma unroll
        for (int r = 0; r < 4; ++r) oacc[m][n][r] *= c;
    }
    __builtin_amdgcn_s_setprio(1);
#pragma unroll
    for (int h2 = 0; h2 < 2; ++h2) {
      bf16x8 vf[4];
#pragma unroll
      for (int m = 0; m < 4; ++m)
        vf[m] = *(const bf16x8*)(Vtlds + (((16 * m + l15) * 512 +
                                          ((kc * 128 + h2 * 64 + g * 16) ^ swzk)) >> 1));
#pragma unroll
      for (int n = 0; n < 4; ++n) {
        union { uint2 u[2]; bf16x8 v; } pf;
        pf.u[0] = pb[2 * h2][n];
        pf.u[1] = pb[2 * h2 + 1][n];
#pragma unroll
        for (int m = 0; m < 4; ++m)
          oacc[m][n] =
              __builtin_amdgcn_mfma_f32_16x16x32_bf16(vf[m], pf.v, oacc[m][n], 0, 0, 0);
      }
    }
    __builtin_amdgcn_s_setprio(0);
  }
  float inv[4];
#pragma unroll
  for (int n = 0; n < 4; ++n) inv[n] = 1.0f / lrun[n];
#pragma unroll
  for (int m = 0; m < 4; ++m)
#pragma unroll
    for (int n = 0; n < 4; ++n) {
      bf16x4 pk;
#pragma unroll
      for (int r = 0; r < 4; ++r) pk[r] = (bf16_t)(oacc[m][n][r] * inv[n]);
      *(bf16x4*)(o + (size_t)(nb + wv * 64 + 16 * n + l15) * 512 + h * 64 + 16 * m +
                 4 * g) = pk;
    }
}

// ---------------- launch ----------------

static inline char* alignp(char* p, size_t a) {
  return (char*)(((uintptr_t)p + a - 1) & ~(uintptr_t)(a - 1));
}

extern "C" void kernel_launch(void* const* d_in, const int* in_sizes, int n_in,
                              void* d_out, int out_size, void* d_ws, size_t ws_size,
                              hipStream_t stream) {
  const float* x = (const float*)d_in[0];
  const float* edge_attr = (const float*)d_in[1];
  const float* gcn_w = (const float*)d_in[2];
  const float* gcn_b = (const float*)d_in[3];
  const float* ep_w = (const float*)d_in[4];
  const float* ep_b = (const float*)d_in[5];
  const float* gate_w = (const float*)d_in[6];
  const float* gate_b = (const float*)d_in[7];
  const float* n1_g = (const float*)d_in[8];
  const float* n1_b = (const float*)d_in[9];
  const float* in_w = (const float*)d_in[10];
  const float* in_b = (const float*)d_in[11];
  const float* out_w = (const float*)d_in[12];
  const float* out_b = (const float*)d_in[13];
  const float* tn_g = (const float*)d_in[14];
  const float* tn_b = (const float*)d_in[15];
  const float* m_w1 = (const float*)d_in[16];
  const float* m_b1 = (const float*)d_in[17];
  const float* m_w2 = (const float*)d_in[18];
  const float* m_b2 = (const float*)d_in[19];
  const float* fn_g = (const float*)d_in[20];
  const float* fn_b = (const float*)d_in[21];
  const int* eidx = (const int*)d_in[22];
  const int* src = eidx;
  const int* dst = eidx + EE;

  float* ws = (float*)d_ws;
  float* R1 = ws;
  float* R2 = R1 + (size_t)NN * 3 * CC;
  float* R3 = R2 + (size_t)NN * CC;
  float* R4 = R3 + (size_t)NN * CC;
  float* dinv = R4 + (size_t)NN * CC;
  int* ip = (int*)(dinv + NN);
  int* ghist = ip;      ip += 64;
  int* gstart = ip;     ip += 65;
  int* gcur = ip;       ip += 64;
  int* elist_src = ip;  ip += EE;
  int* nid_src = ip;    ip += EE + 32;
  int* start_src = ip;  ip += NN + 1;
  int* start_dst = ip;  ip += NN + 1;
  char* bp = alignp((char*)ip, 64);
  int2* grec = (int2*)bp;             bp += (size_t)EE * 8;
  float* ewg = (float*)bp;            bp += (size_t)EE * 4;
  float2* dstrec = (float2*)bp;       bp += (size_t)EE * 8;
  bf16_t* x2b = (bf16_t*)bp;          bp += (size_t)NN * CC * 2;
  bf16_t* gcn_wt = (bf16_t*)bp;       bp += (size_t)CC * CC * 2;
  bf16_t* gate_wt = (bf16_t*)bp;      bp += (size_t)CC * 2 * CC * 2;
  bf16_t* in_wt = (bf16_t*)bp;        bp += (size_t)3 * CC * CC * 2;
  bf16_t* out_wt = (bf16_t*)bp;       bp += (size_t)CC * CC * 2;
  bf16_t* m_w1t = (bf16_t*)bp;        bp += (size_t)2 * CC * CC * 2;
  bf16_t* m_w2t = (bf16_t*)bp;        bp += (size_t)CC * 2 * CC * 2;

  bf16_t* xb = (bf16_t*)R1;      // bf16(x)
  bf16_t* xcefb = (bf16_t*)R1;   // [x_conv | ef] bf16 N x 2C
  bf16_t* qkvb = (bf16_t*)R1;    // qkv bf16 N x 1536
  bf16_t* hb = (bf16_t*)R1;      // mlp hidden bf16 N x 2C
  bf16_t* eacsr = (bf16_t*)((char*)R1 + (size_t)64 * 1024 * 1024);  // 16.8MB
  bf16_t* xwT = (bf16_t*)R2;     // (x@gcn_w)^T bf16 [512][16384]
  bf16_t* gpreb = (bf16_t*)R2;   // gate pre-act bf16 (after xwT dead)
  bf16_t* ob = (bf16_t*)R2;      // attn out bf16 (first half of R2)
  bf16_t* vt = ob + (size_t)NN * CC;  // V^T packed (second half of R2)
  bf16_t* x3b = (bf16_t*)R2;     // bf16(x3) (after ob dead)
  bf16_t* AnFull = (bf16_t*)R3;  // dense adjacency bf16 [16384][256] (8MB)
  bf16_t* oprjb = (bf16_t*)R4;   // out-proj bf16
  float* yf = R4;                // mlp2 f32 out (after oprjb dead)

  // --- edge prep ---
  init_kernel<<<1, 256, 0, stream>>>(ghist, nid_src, eacsr);
  edge_pass1<<<EE / 256, 256, 0, stream>>>(dst, ghist);
  gexscan_kernel<<<1, 64, 0, stream>>>(ghist, gstart, gcur);
  graph_scatter_kernel<<<EE / 2048, 256, 0, stream>>>(src, dst, edge_attr, gcur,
                                                      grec, ewg);
  graph_sort2_kernel<<<128, 1024, 0, stream>>>(grec, ewg, gstart, elist_src, nid_src,
                                               start_src, dstrec, start_dst, dinv);
  ea_gather_kernel<<<(EE * 2 + 255) / 256, 256, 0, stream>>>(edge_attr, elist_src,
                                                             eacsr);
  an_build_kernel<<<128, 256, 0, stream>>>(dstrec, start_dst, dinv, AnFull);

  // --- weight transposes ---
  wt_kernel<<<dim3(CC / 32, CC / 32), 256, 0, stream>>>(gcn_w, gcn_wt, CC, CC);
  wt_kernel<<<dim3(CC / 32, 2 * CC / 32), 256, 0, stream>>>(gate_w, gate_wt, 2 * CC, CC);
  wt_kernel<<<dim3(3 * CC / 32, CC / 32), 256, 0, stream>>>(in_w, in_wt, CC, 3 * CC);
  wt_kernel<<<dim3(CC / 32, CC / 32), 256, 0, stream>>>(out_w, out_wt, CC, CC);
  wt_kernel<<<dim3(2 * CC / 32, CC / 32), 256, 0, stream>>>(m_w1, m_w1t, CC, 2 * CC);
  wt_kernel<<<dim3(CC / 32, 2 * CC / 32), 256, 0, stream>>>(m_w2, m_w2t, 2 * CC, CC);

  // --- GCN conv: xwT = (x @ gcn_w)^T via flipped GEMM, then dense An GEMM ---
  cvt_bf16_kernel<<<(NN * CC / 4 + 255) / 256, 256, 0, stream>>>(x, xb, NN * CC / 4);
  gemm_bf16_kernel<0, 1><<<dim3(NN / 128, CC / 128), 512, 0, stream>>>(
      gcn_wt, xb, nullptr, xwT, CC, NN, CC);
  an_gemm_kernel<<<dim3(CC / 128, NN / 128), 512, 0, stream>>>(AnFull, xwT, gcn_b,
                                                               xcefb);
  ef_mfma_kernel<<<NN / 16, 512, 0, stream>>>(eacsr, ep_w, ep_b, nid_src, start_src,
                                              xcefb);
  dim3 gA(CC / 128, NN / 128);
  gemm_bf16_kernel<0, 1><<<gA, 512, 0, stream>>>(xcefb, gate_wt, nullptr, gpreb, NN,
                                                 CC, 2 * CC);
  ln_gate_kernel<<<NN, 128, 0, stream>>>(gpreb, gate_b, xcefb, n1_g, n1_b, x, x2b);

  // --- MHA ---
  dim3 gQ(3 * CC / 128, NN / 128);
  gemm_bf16_kernel<0, 1><<<gQ, 512, 0, stream>>>(x2b, in_wt, in_b, qkvb, NN, 3 * CC, CC);
  vt_pack_kernel<<<BB * HH, 256, 0, stream>>>(qkvb, vt);
  attn_mfma_kernel<<<BB * HH, 256, 0, stream>>>(qkvb, vt, ob);
  gemm_bf16_kernel<0, 1><<<gA, 512, 0, stream>>>(ob, out_wt, out_b, oprjb, NN, CC, CC);
  ln_addT_kernel<1, 1, 0><<<NN, 128, 0, stream>>>(x2b, oprjb, tn_g, tn_b, nullptr, x3b);

  // --- MLP ---
  dim3 gH(2 * CC / 128, NN / 128);
  gemm_bf16_kernel<1, 1><<<gH, 512, 0, stream>>>(x3b, m_w1t, m_b1, hb, NN, 2 * CC, CC);
  gemm_bf16_kernel<0, 0><<<gA, 512, 0, stream>>>(hb, m_w2t, m_b2, yf, NN, CC, 2 * CC);
  ln_addT_kernel<1, 0, 1><<<NN, 128, 0, stream>>>(x3b, yf, fn_g, fn_b, (float*)d_out,
                                                  nullptr);
}

// Round 19
// 405.071 us; speedup vs baseline: 1.1062x; 1.0287x over previous
//
#include <hip/hip_runtime.h>

#define NN 16384
#define CC 512
#define EE 524288
#define BB 64
#define HH 8
#define EFD 16
#define GEMAXE 10240

typedef __bf16 bf16_t;
typedef __bf16 bf16x4 __attribute__((ext_vector_type(4)));
typedef __bf16 bf16x8 __attribute__((ext_vector_type(8)));
typedef float f32x4v __attribute__((ext_vector_type(4)));

__device__ __forceinline__ float2 ldb2(const bf16_t* p) {
  unsigned w = *(const unsigned*)p;
  return make_float2(__uint_as_float(w << 16), __uint_as_float(w & 0xFFFF0000u));
}

__device__ __forceinline__ float4 ldb4(const bf16_t* p) {
  uint2 w = *(const uint2*)p;
  return make_float4(__uint_as_float(w.x << 16), __uint_as_float(w.x & 0xFFFF0000u),
                     __uint_as_float(w.y << 16), __uint_as_float(w.y & 0xFFFF0000u));
}

// XCD-aware chunked swizzle (nwg % 8 == 0 for all our grids)
__device__ __forceinline__ int2 xcd_swizzle() {
  int nwg = gridDim.x * gridDim.y;
  int bid = blockIdx.y * gridDim.x + blockIdx.x;
  int wg = (bid & 7) * (nwg >> 3) + (bid >> 3);
  return make_int2(wg % gridDim.x, wg / gridDim.x);
}

// ---------------- init / edge pre-pass ----------------

__global__ void init_kernel(int* ghist, int* nid_src, bf16_t* eacsr) {
  int i = threadIdx.x;
  if (i < 64) ghist[i] = 0;
  if (i < 32) nid_src[EE + i] = -1;               // pad for ef chunk tail
  ((int*)(eacsr + (size_t)EE * 16))[i] = 0;       // zero eacsr pad rows (256 ints)
}

// per-graph histogram only (LDS-aggregated)
__global__ __launch_bounds__(256) void edge_pass1(const int* __restrict__ dst,
                                                  int* ghist) {
  __shared__ int h[64];
  int tid = threadIdx.x;
  if (tid < 64) h[tid] = 0;
  __syncthreads();
  int e = blockIdx.x * 256 + tid;  // EE % 256 == 0
  atomicAdd(&h[dst[e] >> 8], 1);
  __syncthreads();
  if (tid < 64 && h[tid]) atomicAdd(&ghist[tid], h[tid]);
}

__global__ void gexscan_kernel(const int* __restrict__ ghist, int* __restrict__ gstart,
                               int* __restrict__ gcur) {
  if (threadIdx.x == 0) {
    int s = 0;
    for (int g = 0; g < 64; ++g) { gstart[g] = s; gcur[g] = s; s += ghist[g]; }
    gstart[64] = s;
  }
}

// bucket edges by graph with block-aggregated offsets; emit packed records.
__global__ __launch_bounds__(256) void graph_scatter_kernel(
    const int* __restrict__ src, const int* __restrict__ dst,
    const float* __restrict__ ea, int* gcur, int2* __restrict__ grec,
    float* __restrict__ ewg) {
  __shared__ int h[64], base[64], h2[64];
  int tid = threadIdx.x;
  if (tid < 64) { h[tid] = 0; h2[tid] = 0; }
  __syncthreads();
  int e0 = blockIdx.x * 2048;
  int gloc[8];
#pragma unroll
  for (int k = 0; k < 8; ++k) {
    gloc[k] = dst[e0 + k * 256 + tid] >> 8;
    atomicAdd(&h[gloc[k]], 1);
  }
  __syncthreads();
  if (tid < 64) base[tid] = h[tid] ? atomicAdd(&gcur[tid], h[tid]) : 0;
  __syncthreads();
#pragma unroll
  for (int k = 0; k < 8; ++k) {
    int e = e0 + k * 256 + tid;
    int g = gloc[k];
    int p = atomicAdd(&h2[g], 1);
    int pos = base[g] + p;
    int ls = src[e] & 255;
    int ld = dst[e] & 255;
    grec[pos] = make_int2(e | (ls << 19), ld);
    const float4* pa = (const float4*)(ea + (size_t)e * EFD);
    float s = 0.f;
#pragma unroll
    for (int q = 0; q < 4; ++q) {
      float4 v = pa[q];
      s += v.x * v.x + v.y * v.y + v.z * v.z + v.w * v.w;
    }
    ewg[pos] = sqrtf(s);
  }
}

// per-graph LDS counting sort, 128 blocks: blockIdx<64 -> DST pass, else SRC.
__global__ __launch_bounds__(1024) void graph_sort2_kernel(
    const int2* __restrict__ grec, const float* __restrict__ ewg,
    const int* __restrict__ gstart, int* __restrict__ elist_src,
    int* __restrict__ nid_src, int* __restrict__ start_src,
    float2* __restrict__ dstrec, int* __restrict__ start_dst,
    float* __restrict__ dinv) {
  __shared__ int lbuf[GEMAXE];
  __shared__ unsigned short sl[GEMAXE];
  __shared__ float ewl[GEMAXE];
  __shared__ int h[256], hx[256], h2[256];
  __shared__ float fdinv[256];
  const int g = blockIdx.x & 63;
  const int tid = threadIdx.x;
  const int gs = gstart[g];
  const int cnt = gstart[g + 1] - gs;
  if (tid < 256) { h[tid] = 0; h2[tid] = 0; }
  __syncthreads();
  if (blockIdx.x < 64) {
    for (int i = tid; i < cnt; i += 1024) {
      int2 r = grec[gs + i];
      int ld = r.y;
      sl[i] = (unsigned short)(((r.x >> 19) & 255) | (ld << 8));
      ewl[i] = ewg[gs + i];
      atomicAdd(&h[ld], 1);
    }
    __syncthreads();
    int myc = (tid < 256) ? h[tid] : 0;
    for (int off = 1; off < 256; off <<= 1) {
      int v = (tid < 256 && tid >= off) ? h[tid - off] : 0;
      __syncthreads();
      if (tid < 256) h[tid] += v;
      __syncthreads();
    }
    if (tid < 256) {
      hx[tid] = h[tid] - myc;
      start_dst[g * 256 + tid] = gs + hx[tid];
    }
    if (g == 63 && tid == 0) start_dst[NN] = EE;
    __syncthreads();
    for (int i = tid; i < cnt; i += 1024) {
      int ld = sl[i] >> 8;
      int p = hx[ld] + atomicAdd(&h2[ld], 1);
      lbuf[p] = i;
    }
    __syncthreads();
    if (tid < 256) {
      float dg = 1.0f;
      int s0 = hx[tid], e0 = s0 + myc;
      for (int i = s0; i < e0; ++i) dg += ewl[lbuf[i]];
      float dv = rsqrtf(fmaxf(dg, 1e-12f));
      fdinv[tid] = dv;
      dinv[g * 256 + tid] = dv;
    }
    __syncthreads();
    for (int p = tid; p < cnt; p += 1024) {
      int i = lbuf[p];
      int ls = sl[i] & 255;
      int ld = sl[i] >> 8;
      dstrec[gs + p] =
          make_float2(fdinv[ls] * ewl[i] * fdinv[ld], __int_as_float(ls));
    }
  } else {
    int* wb = (int*)ewl;
    for (int i = tid; i < cnt; i += 1024) {
      int w = grec[gs + i].x;
      wb[i] = w;
      atomicAdd(&h[w >> 19], 1);
    }
    __syncthreads();
    int myc = (tid < 256) ? h[tid] : 0;
    for (int off = 1; off < 256; off <<= 1) {
      int v = (tid < 256 && tid >= off) ? h[tid - off] : 0;
      __syncthreads();
      if (tid < 256) h[tid] += v;
      __syncthreads();
    }
    if (tid < 256) {
      hx[tid] = h[tid] - myc;
      start_src[g * 256 + tid] = gs + hx[tid];
    }
    if (g == 63 && tid == 0) start_src[NN] = EE;
    __syncthreads();
    for (int i = tid; i < cnt; i += 1024) {
      int w = wb[i];
      int ls = w >> 19;
      int p = hx[ls] + atomicAdd(&h2[ls], 1);
      lbuf[p] = w;
    }
    __syncthreads();
    for (int p = tid; p < cnt; p += 1024) {
      int w = lbuf[p];
      elist_src[gs + p] = w & 0x7FFFF;
      nid_src[gs + p] = g * 256 + (w >> 19);
    }
  }
}

// gather edge_attr rows into CSR order as bf16
__global__ void ea_gather_kernel(const float* __restrict__ ea,
                                 const int* __restrict__ elist,
                                 bf16_t* __restrict__ eacsr) {
  int idx = blockIdx.x * 256 + threadIdx.x;
  if (idx >= EE * 2) return;
  int pos = idx >> 1, half = idx & 1;
  int e = elist[pos];
  const f32x4v* p = (const f32x4v*)(ea + (size_t)e * EFD + half * 8);
  f32x4v u0 = p[0], u1 = p[1];
  bf16x8 f;
#pragma unroll
  for (int r = 0; r < 4; ++r) {
    f[r] = (bf16_t)u0[r];
    f[4 + r] = (bf16_t)u1[r];
  }
  *(bf16x8*)(eacsr + (size_t)pos * 16 + half * 8) = f;
}

// ---------------- dense per-graph adjacency build ----------------
__global__ __launch_bounds__(256) void an_build_kernel(
    const float2* __restrict__ dstrec, const int* __restrict__ start_dst,
    const float* __restrict__ dinv, bf16_t* __restrict__ An) {
  __shared__ float AnS[128][256];  // 128 KB
  const int g = blockIdx.x >> 1, h = blockIdx.x & 1;
  const int tid = threadIdx.x;
  float4* az = (float4*)&AnS[0][0];
  for (int i = tid; i < 128 * 256 / 4; i += 256)
    az[i] = make_float4(0.f, 0.f, 0.f, 0.f);
  __syncthreads();
  const int nbase = g * 256 + h * 128;
  if (tid < 128) {
    int node = nbase + tid;
    int st = start_dst[node], en = start_dst[node + 1];
    float* row = AnS[tid];
    for (int p = st; p < en; ++p) {
      float2 r = dstrec[p];
      row[__float_as_int(r.y)] += r.x;
    }
    float dv = dinv[node];
    row[h * 128 + tid] += dv * dv;
  }
  __syncthreads();
  bf16_t* out = An + (size_t)nbase * 256;
  const float* s0 = &AnS[0][0];
  for (int i = tid; i < 128 * 256 / 8; i += 256) {
    bf16x8 v;
#pragma unroll
    for (int r = 0; r < 8; ++r) v[r] = (bf16_t)s0[i * 8 + r];
    *(bf16x8*)(out + i * 8) = v;
  }
}

// ---------------- fused prep: cvt(x) + 6 weight transposes ----------------
__device__ __forceinline__ void wt_tile(const float* __restrict__ W,
                                        bf16_t* __restrict__ Wt, int K, int N,
                                        int bx, int by, float tile[32][33]) {
  int tx = threadIdx.x & 31, ty = threadIdx.x >> 5;
  int x0 = bx * 32, y0 = by * 32;
#pragma unroll
  for (int i = 0; i < 32; i += 8)
    tile[ty + i][tx] = W[(size_t)(y0 + ty + i) * N + x0 + tx];
  __syncthreads();
#pragma unroll
  for (int i = 0; i < 32; i += 8)
    Wt[(size_t)(x0 + ty + i) * K + y0 + tx] = (bf16_t)tile[tx][ty + i];
}

__global__ __launch_bounds__(256) void prep_kernel(
    const float* __restrict__ x, bf16_t* __restrict__ xb,
    const float* __restrict__ gcn_w, bf16_t* __restrict__ gcn_wt,
    const float* __restrict__ gate_w, bf16_t* __restrict__ gate_wt,
    const float* __restrict__ in_w, bf16_t* __restrict__ in_wt,
    const float* __restrict__ out_w, bf16_t* __restrict__ out_wt,
    const float* __restrict__ m_w1, bf16_t* __restrict__ m_w1t,
    const float* __restrict__ m_w2, bf16_t* __restrict__ m_w2t) {
  __shared__ float tile[32][33];
  int b = blockIdx.x;
  if (b < 8192) {  // cvt: NN*CC/4 = 2M float4 over 8192 blocks
    int i = b * 256 + threadIdx.x;
    float4 v = ((const float4*)x)[i];
    bf16x4 o;
    o[0] = (bf16_t)v.x; o[1] = (bf16_t)v.y; o[2] = (bf16_t)v.z; o[3] = (bf16_t)v.w;
    ((bf16x4*)xb)[i] = o;
    return;
  }
  b -= 8192;
  if (b < 256)        wt_tile(gcn_w, gcn_wt, CC, CC, b % 16, b / 16, tile);
  else if (b < 768)   { b -= 256;  wt_tile(gate_w, gate_wt, 2 * CC, CC, b % 16, b / 16, tile); }
  else if (b < 1536)  { b -= 768;  wt_tile(in_w, in_wt, CC, 3 * CC, b % 48, b / 48, tile); }
  else if (b < 1792)  { b -= 1536; wt_tile(out_w, out_wt, CC, CC, b % 16, b / 16, tile); }
  else if (b < 2304)  { b -= 1792; wt_tile(m_w1, m_w1t, CC, 2 * CC, b % 32, b / 32, tile); }
  else                { b -= 2304; wt_tile(m_w2, m_w2t, 2 * CC, CC, b % 16, b / 16, tile); }
}

// ---------------- edge projection via double-MFMA (prefetched) -------------
__global__ __launch_bounds__(512) void ef_mfma_kernel(
    const bf16_t* __restrict__ eacsr, const float* __restrict__ ep_w,
    const float* __restrict__ ep_b, const int* __restrict__ nid,
    const int* __restrict__ start, bf16_t* __restrict__ efb) {
  const int tid = threadIdx.x;
  const int lane = tid & 63;
  const int wv = tid >> 6;      // 0..7
  const int l15 = lane & 15;
  const int g = lane >> 4;
  const int n0 = blockIdx.x * 16;
  const int cbase = wv * 64;

  bf16x8 wfr[4];
#pragma unroll
  for (int t = 0; t < 4; ++t) {
    bf16x8 f = {};
    int c = cbase + t * 16 + l15;
    if (g < 2) {
#pragma unroll
      for (int j = 0; j < 8; ++j) f[j] = (bf16_t)ep_w[(g * 8 + j) * CC + c];
    } else if (g == 2) {
      f[0] = (bf16_t)ep_b[c];
    }
    wfr[t] = f;
  }

  const int st = start[n0];
  const int en = start[n0 + 16];
  const int tgt = n0 + l15;

  f32x4v eacc[4] = {};

  // prefetch state (T14 issue-early pattern)
  bf16x8 afP0 = {}, afP1 = {};
  int4 idloP, idhiP;
  if (st < en) {
    if (g < 2) {
      afP0 = *(const bf16x8*)(eacsr + (size_t)(st + l15) * 16 + g * 8);
      afP1 = *(const bf16x8*)(eacsr + (size_t)(st + 16 + l15) * 16 + g * 8);
    } else if (g == 2) {
      afP0[0] = (bf16_t)1.0f;
      afP1[0] = (bf16_t)1.0f;
    }
    idloP = *(const int4*)(nid + st + g * 4);
    idhiP = *(const int4*)(nid + st + 16 + g * 4);
  }

  for (int cb = st; cb < en; cb += 32) {
    bf16x8 af0 = afP0, af1 = afP1;
    int4 idlo = idloP, idhi = idhiP;
    if (cb + 32 < en) {
      int nb2 = cb + 32;
      if (g < 2) {
        afP0 = *(const bf16x8*)(eacsr + (size_t)(nb2 + l15) * 16 + g * 8);
        afP1 = *(const bf16x8*)(eacsr + (size_t)(nb2 + 16 + l15) * 16 + g * 8);
      }
      idloP = *(const int4*)(nid + nb2 + g * 4);
      idhiP = *(const int4*)(nid + nb2 + 16 + g * 4);
    }
    bf16x8 sf;
    sf[0] = (idlo.x == tgt) ? (bf16_t)1.0f : (bf16_t)0.0f;
    sf[1] = (idlo.y == tgt) ? (bf16_t)1.0f : (bf16_t)0.0f;
    sf[2] = (idlo.z == tgt) ? (bf16_t)1.0f : (bf16_t)0.0f;
    sf[3] = (idlo.w == tgt) ? (bf16_t)1.0f : (bf16_t)0.0f;
    sf[4] = (idhi.x == tgt) ? (bf16_t)1.0f : (bf16_t)0.0f;
    sf[5] = (idhi.y == tgt) ? (bf16_t)1.0f : (bf16_t)0.0f;
    sf[6] = (idhi.z == tgt) ? (bf16_t)1.0f : (bf16_t)0.0f;
    sf[7] = (idhi.w == tgt) ? (bf16_t)1.0f : (bf16_t)0.0f;
    __builtin_amdgcn_s_setprio(1);
#pragma unroll
    for (int t = 0; t < 4; ++t) {
      f32x4v s0 = {}, s1 = {};
      s0 = __builtin_amdgcn_mfma_f32_16x16x32_bf16(af0, wfr[t], s0, 0, 0, 0);
      s1 = __builtin_amdgcn_mfma_f32_16x16x32_bf16(af1, wfr[t], s1, 0, 0, 0);
      union { bf16x8 v; bf16x4 h[2]; } pf;
#pragma unroll
      for (int r = 0; r < 4; ++r) {
        pf.h[0][r] = (bf16_t)fmaxf(s0[r], 0.f);
        pf.h[1][r] = (bf16_t)fmaxf(s1[r], 0.f);
      }
      eacc[t] = __builtin_amdgcn_mfma_f32_16x16x32_bf16(sf, pf.v, eacc[t], 0, 0, 0);
    }
    __builtin_amdgcn_s_setprio(0);
  }
#pragma unroll
  for (int t = 0; t < 4; ++t) {
    int c = cbase + t * 16 + l15;
#pragma unroll
    for (int r = 0; r < 4; ++r) {
      int node = n0 + g * 4 + r;
      efb[(size_t)node * (2 * CC) + CC + c] = (bf16_t)eacc[t][r];
    }
  }
}

// ---------------- bf16 MFMA GEMM: BK=64, swizzled LDS, XCD, 8 waves --------
__device__ __forceinline__ void gl_lds16(const bf16_t* g, bf16_t* l) {
  __builtin_amdgcn_global_load_lds(
      (const __attribute__((address_space(1))) void*)g,
      (__attribute__((address_space(3))) void*)l, 16, 0, 0);
}

// 128x128 tile, 512 threads (8 waves as 4Mx2N, per-wave 32x64 out).
// LDS [128][64] bf16; slot sl of row r holds global k-slot sl^(r&7).
template <int ACT, int OUT>
__global__ __launch_bounds__(512) void gemm_bf16_kernel(
    const bf16_t* __restrict__ A, const bf16_t* __restrict__ Bt,
    const float* __restrict__ bias, void* __restrict__ Cout, int M, int N, int K) {
  __shared__ __align__(16) bf16_t Al[128 * 64];
  __shared__ __align__(16) bf16_t Bl[128 * 64];
  const int tid = threadIdx.x;
  const int lane = tid & 63;
  const int wave = tid >> 6;
  int2 sw = xcd_swizzle();
  const int row0 = sw.y * 128;
  const int col0 = sw.x * 128;
  const int wm = wave >> 1;   // 0..3 (32 rows each)
  const int wn = wave & 1;    // 0..1 (64 cols each)
  f32x4v acc[2][4] = {};
  const int srow = tid >> 3;
  const int sslot = (tid & 7) ^ (srow & 7);
  const bf16_t* aBase = A + (size_t)(row0 + srow) * K + sslot * 8;
  const bf16_t* bBase = Bt + (size_t)(col0 + srow) * K + sslot * 8;
  const int fr = lane & 15;
  const int g = lane >> 4;
  const int f7 = fr & 7;
  for (int k0 = 0; k0 < K; k0 += 64) {
    gl_lds16(aBase + k0, Al + tid * 8);
    gl_lds16(aBase + (size_t)64 * K + k0, Al + 4096 + tid * 8);
    gl_lds16(bBase + k0, Bl + tid * 8);
    gl_lds16(bBase + (size_t)64 * K + k0, Bl + 4096 + tid * 8);
    __syncthreads();
#pragma unroll
    for (int s = 0; s < 2; ++s) {
      const int sl = ((s * 4 + g) ^ f7) * 8;
      bf16x8 af[2], bfv[4];
#pragma unroll
      for (int m = 0; m < 2; ++m)
        af[m] = *(const bf16x8*)(Al + (wm * 32 + m * 16 + fr) * 64 + sl);
#pragma unroll
      for (int n = 0; n < 4; ++n)
        bfv[n] = *(const bf16x8*)(Bl + (wn * 64 + n * 16 + fr) * 64 + sl);
#pragma unroll
      for (int m = 0; m < 2; ++m)
#pragma unroll
        for (int n = 0; n < 4; ++n)
          acc[m][n] = __builtin_amdgcn_mfma_f32_16x16x32_bf16(af[m], bfv[n],
                                                              acc[m][n], 0, 0, 0);
    }
    __syncthreads();
  }
  const int fq = (lane >> 4) * 4;
#pragma unroll
  for (int m = 0; m < 2; ++m) {
    int grb = row0 + wm * 32 + m * 16 + fq;
#pragma unroll
    for (int n = 0; n < 4; ++n) {
      int gc = col0 + wn * 64 + n * 16 + fr;
      float bv = bias ? bias[gc] : 0.f;
#pragma unroll
      for (int r = 0; r < 4; ++r) {
        float v = acc[m][n][r] + bv;
        if (ACT == 1) v = v / (1.f + __expf(-v));
        if (OUT == 0)
          ((float*)Cout)[(size_t)(grb + r) * N + gc] = v;
        else
          ((bf16_t*)Cout)[(size_t)(grb + r) * N + gc] = (bf16_t)v;
      }
    }
  }
}

// ---------------- block-diagonal An GEMM (BK=64, swizzled, 8 waves) --------
__global__ __launch_bounds__(512) void an_gemm_kernel(
    const bf16_t* __restrict__ An, const bf16_t* __restrict__ xwT,
    const float* __restrict__ bias, bf16_t* __restrict__ outb) {
  __shared__ __align__(16) bf16_t Al[128 * 64];
  __shared__ __align__(16) bf16_t Bl[128 * 64];
  const int tid = threadIdx.x;
  const int lane = tid & 63;
  const int wave = tid >> 6;
  int2 sw = xcd_swizzle();
  const int row0 = sw.y * 128;  // node rows
  const int col0 = sw.x * 128;  // chan cols
  const int gr = row0 >> 8;     // graph
  const int wm = wave >> 1;
  const int wn = wave & 1;
  f32x4v acc[2][4] = {};
  const int srow = tid >> 3;
  const int sslot = (tid & 7) ^ (srow & 7);
  const bf16_t* aBase = An + (size_t)(row0 + srow) * 256 + sslot * 8;
  const bf16_t* bBase = xwT + (size_t)(col0 + srow) * NN + gr * 256 + sslot * 8;
  const int fr = lane & 15;
  const int g = lane >> 4;
  const int f7 = fr & 7;
  for (int k0 = 0; k0 < 256; k0 += 64) {
    gl_lds16(aBase + k0, Al + tid * 8);
    gl_lds16(aBase + (size_t)64 * 256 + k0, Al + 4096 + tid * 8);
    gl_lds16(bBase + k0, Bl + tid * 8);
    gl_lds16(bBase + (size_t)64 * NN + k0, Bl + 4096 + tid * 8);
    __syncthreads();
#pragma unroll
    for (int s = 0; s < 2; ++s) {
      const int sl = ((s * 4 + g) ^ f7) * 8;
      bf16x8 af[2], bfv[4];
#pragma unroll
      for (int m = 0; m < 2; ++m)
        af[m] = *(const bf16x8*)(Al + (wm * 32 + m * 16 + fr) * 64 + sl);
#pragma unroll
      for (int n = 0; n < 4; ++n)
        bfv[n] = *(const bf16x8*)(Bl + (wn * 64 + n * 16 + fr) * 64 + sl);
#pragma unroll
      for (int m = 0; m < 2; ++m)
#pragma unroll
        for (int n = 0; n < 4; ++n)
          acc[m][n] = __builtin_amdgcn_mfma_f32_16x16x32_bf16(af[m], bfv[n],
                                                              acc[m][n], 0, 0, 0);
    }
    __syncthreads();
  }
  const int fq = (lane >> 4) * 4;
#pragma unroll
  for (int m = 0; m < 2; ++m) {
    int grb = row0 + wm * 32 + m * 16 + fq;
#pragma unroll
    for (int n = 0; n < 4; ++n) {
      int gc = col0 + wn * 64 + n * 16 + fr;
      float bv = bias[gc];
#pragma unroll
      for (int r = 0; r < 4; ++r)
        outb[(size_t)(grb + r) * (2 * CC) + gc] = (bf16_t)(acc[m][n][r] + bv);
    }
  }
}

// ---------------- layernorm fused kernels (128 thr/row, float4) ------------

__device__ inline void block_reduce2_2w(float& s, float& q, float* red) {
#pragma unroll
  for (int off = 32; off >= 1; off >>= 1) {
    s += __shfl_xor(s, off, 64);
    q += __shfl_xor(q, off, 64);
  }
  int wid = threadIdx.x >> 6;
  if ((threadIdx.x & 63) == 0) { red[wid * 2] = s; red[wid * 2 + 1] = q; }
  __syncthreads();
  s = red[0] + red[2];
  q = red[1] + red[3];
}

// out = LN(A + B) * g + be ; IA/IB: 1 = bf16 input; WF: 1 = f32 out, else bf16
template <int IA, int IB, int WF>
__global__ __launch_bounds__(128) void ln_addT_kernel(
    const void* __restrict__ A, const void* __restrict__ Bv,
    const float* __restrict__ g, const float* __restrict__ be,
    float* __restrict__ outf, bf16_t* __restrict__ outb) {
  int row = blockIdx.x, tid = threadIdx.x, c0 = tid * 4;
  __shared__ float red[4];
  float4 a = IA ? ldb4((const bf16_t*)A + (size_t)row * CC + c0)
                : *(const float4*)((const float*)A + (size_t)row * CC + c0);
  float4 b = IB ? ldb4((const bf16_t*)Bv + (size_t)row * CC + c0)
                : *(const float4*)((const float*)Bv + (size_t)row * CC + c0);
  float x0 = a.x + b.x, x1 = a.y + b.y, x2 = a.z + b.z, x3 = a.w + b.w;
  float s = (x0 + x1) + (x2 + x3);
  float q = (x0 * x0 + x1 * x1) + (x2 * x2 + x3 * x3);
  block_reduce2_2w(s, q, red);
  float mean = s * (1.f / CC);
  float var = q * (1.f / CC) - mean * mean;
  float rs = rsqrtf(var + 1e-5f);
  float4 gg = *(const float4*)(g + c0);
  float4 bb = *(const float4*)(be + c0);
  float o0 = (x0 - mean) * rs * gg.x + bb.x;
  float o1 = (x1 - mean) * rs * gg.y + bb.y;
  float o2 = (x2 - mean) * rs * gg.z + bb.z;
  float o3 = (x3 - mean) * rs * gg.w + bb.w;
  if (WF) {
    *(float4*)(outf + (size_t)row * CC + c0) = make_float4(o0, o1, o2, o3);
  } else {
    bf16x4 pk;
    pk[0] = (bf16_t)o0; pk[1] = (bf16_t)o1; pk[2] = (bf16_t)o2; pk[3] = (bf16_t)o3;
    *(bf16x4*)(outb + (size_t)row * CC + c0) = pk;
  }
}

// gate+mix+LN+relu+residual; bf16 inputs (gpre, xc|ef), f32 x residual; bf16 out
__global__ __launch_bounds__(128) void ln_gate_kernel(
    const bf16_t* __restrict__ gpreb, const float* __restrict__ gate_b,
    const bf16_t* __restrict__ xcef, const float* __restrict__ n1g,
    const float* __restrict__ n1b, const float* __restrict__ xin,
    bf16_t* __restrict__ x2b) {
  int row = blockIdx.x, tid = threadIdx.x, c0 = tid * 4;
  __shared__ float red[4];
  float4 gp = ldb4(gpreb + (size_t)row * CC + c0);
  float4 xcv = ldb4(xcef + (size_t)row * (2 * CC) + c0);
  float4 efv = ldb4(xcef + (size_t)row * (2 * CC) + CC + c0);
  float4 gb = *(const float4*)(gate_b + c0);
  float g0 = 1.f / (1.f + __expf(-(gp.x + gb.x)));
  float g1 = 1.f / (1.f + __expf(-(gp.y + gb.y)));
  float g2 = 1.f / (1.f + __expf(-(gp.z + gb.z)));
  float g3 = 1.f / (1.f + __expf(-(gp.w + gb.w)));
  float x0 = g0 * xcv.x + (1.f - g0) * efv.x;
  float x1 = g1 * xcv.y + (1.f - g1) * efv.y;
  float x2 = g2 * xcv.z + (1.f - g2) * efv.z;
  float x3 = g3 * xcv.w + (1.f - g3) * efv.w;
  float s = (x0 + x1) + (x2 + x3);
  float q = (x0 * x0 + x1 * x1) + (x2 * x2 + x3 * x3);
  block_reduce2_2w(s, q, red);
  float mean = s * (1.f / CC);
  float var = q * (1.f / CC) - mean * mean;
  float rs = rsqrtf(var + 1e-5f);
  float4 ng = *(const float4*)(n1g + c0);
  float4 nb = *(const float4*)(n1b + c0);
  float4 xi = *(const float4*)(xin + (size_t)row * CC + c0);
  float o0 = fmaxf((x0 - mean) * rs * ng.x + nb.x, 0.f) + xi.x;
  float o1 = fmaxf((x1 - mean) * rs * ng.y + nb.y, 0.f) + xi.y;
  float o2 = fmaxf((x2 - mean) * rs * ng.z + nb.z, 0.f) + xi.z;
  float o3 = fmaxf((x3 - mean) * rs * ng.w + nb.w, 0.f) + xi.w;
  bf16x4 pk;
  pk[0] = (bf16_t)o0; pk[1] = (bf16_t)o1; pk[2] = (bf16_t)o2; pk[3] = (bf16_t)o3;
  *(bf16x4*)(x2b + (size_t)row * CC + c0) = pk;
}

// ---------------- V^T pack (pre-swizzled + pi-permuted K for attn) ---------
__global__ __launch_bounds__(256) void vt_pack_kernel(const bf16_t* __restrict__ qkvb,
                                                      bf16_t* __restrict__ vt) {
  int b = blockIdx.x >> 3, h = blockIdx.x & 7;
  int nb = b * 256;
  size_t voff = 1024 + (size_t)h * 64;
  char* out = (char*)(vt + (size_t)blockIdx.x * (64 * 256));
  __shared__ bf16_t tile[64][80];
  int tid = threadIdx.x;
  for (int kb = 0; kb < 4; ++kb) {
    __syncthreads();
#pragma unroll
    for (int p = 0; p < 2; ++p) {
      int k = p * 32 + (tid >> 3);
      int d8 = tid & 7;
      bf16x8 v = *(const bf16x8*)(qkvb + (size_t)(nb + kb * 64 + k) * 1536 + voff + d8 * 8);
      *(bf16x8*)(&tile[k][d8 * 8]) = v;
    }
    __syncthreads();
#pragma unroll
    for (int p = 0; p < 2; ++p) {
      int d = p * 32 + (tid >> 3);
      int k8 = tid & 7;
      bf16x8 v;
#pragma unroll
      for (int j = 0; j < 8; ++j) {
        int pos = k8 * 8 + j;
        int sl = pos & 31;
        int srck = (pos & 32) + ((sl >> 3) << 2) + (sl & 3) + (((sl >> 2) & 1) << 4);
        v[j] = tile[srck][d];
      }
      int byteoff = d * 512 + ((kb * 128 + k8 * 16) ^ ((d & 7) << 4));
      *(bf16x8*)(out + byteoff) = v;
    }
  }
}

// ---------------- MFMA attention (shuffle-free PV, setprio) ----------------
__global__ __launch_bounds__(256, 2) void attn_mfma_kernel(
    const bf16_t* __restrict__ qkvb, const bf16_t* __restrict__ vt,
    bf16_t* __restrict__ o) {
  const int b = blockIdx.x >> 3;
  const int h = blockIdx.x & 7;
  const int nb = b * 256;
  const int tid = threadIdx.x;
  const int lane = tid & 63;
  const int wv = tid >> 6;
  const int l15 = lane & 15;
  const int g = lane >> 4;
  const int swzk = (l15 & 7) << 4;
  __shared__ __align__(16) bf16_t Klds[256 * 64];
  __shared__ __align__(16) bf16_t Vtlds[64 * 256];
  const size_t qoff = (size_t)h * 64;
  const size_t koff = 512 + (size_t)h * 64;

  {
    const int dcol = 16 * ((tid & 7) ^ ((tid >> 3) & 7));
    const bf16_t* srcb = qkvb + koff + (dcol >> 1);
#pragma unroll
    for (int i = 0; i < 8; ++i) {
      int k = i * 32 + (tid >> 3);
      gl_lds16(srcb + (size_t)(nb + k) * 1536, Klds + ((i * 4096 + wv * 1024) >> 1));
    }
  }
  {
    const bf16_t* vsrc = vt + (size_t)blockIdx.x * (64 * 256);
#pragma unroll
    for (int i = 0; i < 8; ++i) {
      int base = i * 4096 + wv * 1024;
      gl_lds16(vsrc + ((base >> 1) + lane * 8), Vtlds + (base >> 1));
    }
  }

  bf16x8 qf[4][2];
#pragma unroll
  for (int n = 0; n < 4; ++n) {
    const bf16_t* qp = qkvb + (size_t)(nb + wv * 64 + 16 * n + l15) * 1536 + qoff + g * 8;
    qf[n][0] = *(const bf16x8*)(qp);
    qf[n][1] = *(const bf16x8*)(qp + 32);
  }

  __syncthreads();

  f32x4v oacc[4][4] = {};
  float mrun[4] = {-1e30f, -1e30f, -1e30f, -1e30f};
  float lrun[4] = {0.f, 0.f, 0.f, 0.f};

  for (int kc = 0; kc < 4; ++kc) {
    f32x4v sacc[4][4] = {};
    const int kb128 = (kc * 64 + l15) * 128;
    __builtin_amdgcn_s_setprio(1);
#pragma unroll
    for (int m = 0; m < 4; ++m) {
      bf16x8 a0 = *(const bf16x8*)(Klds + ((kb128 + m * 2048 + ((g * 16) ^ swzk)) >> 1));
      bf16x8 a1 =
          *(const bf16x8*)(Klds + ((kb128 + m * 2048 + ((64 + g * 16) ^ swzk)) >> 1));
#pragma unroll
      for (int n = 0; n < 4; ++n) {
        sacc[m][n] = __builtin_amdgcn_mfma_f32_16x16x32_bf16(a0, qf[n][0], sacc[m][n], 0, 0, 0);
        sacc[m][n] = __builtin_amdgcn_mfma_f32_16x16x32_bf16(a1, qf[n][1], sacc[m][n], 0, 0, 0);
      }
    }
    __builtin_amdgcn_s_setprio(0);
    uint2 pb[4][4];
#pragma unroll
    for (int n = 0; n < 4; ++n) {
      float mx = sacc[0][n][0];
#pragma unroll
      for (int m = 0; m < 4; ++m)
#pragma unroll
        for (int r = 0; r < 4; ++r) mx = fmaxf(mx, sacc[m][n][r]);
      mx = fmaxf(mx, __shfl_xor(mx, 16));
      mx = fmaxf(mx, __shfl_xor(mx, 32));
      float mnew = fmaxf(mrun[n], mx);
      float c = __expf((mrun[n] - mnew) * 0.125f);
      mrun[n] = mnew;
      float s = 0.f;
#pragma unroll
      for (int m = 0; m < 4; ++m) {
        float p0 = __expf((sacc[m][n][0] - mnew) * 0.125f);
        float p1 = __expf((sacc[m][n][1] - mnew) * 0.125f);
        float p2 = __expf((sacc[m][n][2] - mnew) * 0.125f);
        float p3 = __expf((sacc[m][n][3] - mnew) * 0.125f);
        s += (p0 + p1) + (p2 + p3);
        union { bf16x4 v; uint2 u; } cv;
        cv.v[0] = (bf16_t)p0; cv.v[1] = (bf16_t)p1;
        cv.v[2] = (bf16_t)p2; cv.v[3] = (bf16_t)p3;
        pb[m][n] = cv.u;
      }
      s += __shfl_xor(s, 16);
      s += __shfl_xor(s, 32);
      lrun[n] = lrun[n] * c + s;
#pragma unroll
      for (int m = 0; m < 4; ++m)
#pragma unroll
        for (int r = 0; r < 4; ++r) oacc[m][n][r] *= c;
    }
    __builtin_amdgcn_s_setprio(1);
#pragma unroll
    for (int h2 = 0; h2 < 2; ++h2) {
      bf16x8 vf[4];
#pragma unroll
      for (int m = 0; m < 4; ++m)
        vf[m] = *(const bf16x8*)(Vtlds + (((16 * m + l15) * 512 +
                                          ((kc * 128 + h2 * 64 + g * 16) ^ swzk)) >> 1));
#pragma unroll
      for (int n = 0; n < 4; ++n) {
        union { uint2 u[2]; bf16x8 v; } pf;
        pf.u[0] = pb[2 * h2][n];
        pf.u[1] = pb[2 * h2 + 1][n];
#pragma unroll
        for (int m = 0; m < 4; ++m)
          oacc[m][n] =
              __builtin_amdgcn_mfma_f32_16x16x32_bf16(vf[m], pf.v, oacc[m][n], 0, 0, 0);
      }
    }
    __builtin_amdgcn_s_setprio(0);
  }
  float inv[4];
#pragma unroll
  for (int n = 0; n < 4; ++n) inv[n] = 1.0f / lrun[n];
#pragma unroll
  for (int m = 0; m < 4; ++m)
#pragma unroll
    for (int n = 0; n < 4; ++n) {
      bf16x4 pk;
#pragma unroll
      for (int r = 0; r < 4; ++r) pk[r] = (bf16_t)(oacc[m][n][r] * inv[n]);
      *(bf16x4*)(o + (size_t)(nb + wv * 64 + 16 * n + l15) * 512 + h * 64 + 16 * m +
                 4 * g) = pk;
    }
}

// ---------------- launch ----------------

static inline char* alignp(char* p, size_t a) {
  return (char*)(((uintptr_t)p + a - 1) & ~(uintptr_t)(a - 1));
}

extern "C" void kernel_launch(void* const* d_in, const int* in_sizes, int n_in,
                              void* d_out, int out_size, void* d_ws, size_t ws_size,
                              hipStream_t stream) {
  const float* x = (const float*)d_in[0];
  const float* edge_attr = (const float*)d_in[1];
  const float* gcn_w = (const float*)d_in[2];
  const float* gcn_b = (const float*)d_in[3];
  const float* ep_w = (const float*)d_in[4];
  const float* ep_b = (const float*)d_in[5];
  const float* gate_w = (const float*)d_in[6];
  const float* gate_b = (const float*)d_in[7];
  const float* n1_g = (const float*)d_in[8];
  const float* n1_b = (const float*)d_in[9];
  const float* in_w = (const float*)d_in[10];
  const float* in_b = (const float*)d_in[11];
  const float* out_w = (const float*)d_in[12];
  const float* out_b = (const float*)d_in[13];
  const float* tn_g = (const float*)d_in[14];
  const float* tn_b = (const float*)d_in[15];
  const float* m_w1 = (const float*)d_in[16];
  const float* m_b1 = (const float*)d_in[17];
  const float* m_w2 = (const float*)d_in[18];
  const float* m_b2 = (const float*)d_in[19];
  const float* fn_g = (const float*)d_in[20];
  const float* fn_b = (const float*)d_in[21];
  const int* eidx = (const int*)d_in[22];
  const int* src = eidx;
  const int* dst = eidx + EE;

  float* ws = (float*)d_ws;
  float* R1 = ws;
  float* R2 = R1 + (size_t)NN * 3 * CC;
  float* R3 = R2 + (size_t)NN * CC;
  float* R4 = R3 + (size_t)NN * CC;
  float* dinv = R4 + (size_t)NN * CC;
  int* ip = (int*)(dinv + NN);
  int* ghist = ip;      ip += 64;
  int* gstart = ip;     ip += 65;
  int* gcur = ip;       ip += 64;
  int* elist_src = ip;  ip += EE;
  int* nid_src = ip;    ip += EE + 32;
  int* start_src = ip;  ip += NN + 1;
  int* start_dst = ip;  ip += NN + 1;
  char* bp = alignp((char*)ip, 64);
  int2* grec = (int2*)bp;             bp += (size_t)EE * 8;
  float* ewg = (float*)bp;            bp += (size_t)EE * 4;
  float2* dstrec = (float2*)bp;       bp += (size_t)EE * 8;
  bf16_t* x2b = (bf16_t*)bp;          bp += (size_t)NN * CC * 2;
  bf16_t* gcn_wt = (bf16_t*)bp;       bp += (size_t)CC * CC * 2;
  bf16_t* gate_wt = (bf16_t*)bp;      bp += (size_t)CC * 2 * CC * 2;
  bf16_t* in_wt = (bf16_t*)bp;        bp += (size_t)3 * CC * CC * 2;
  bf16_t* out_wt = (bf16_t*)bp;       bp += (size_t)CC * CC * 2;
  bf16_t* m_w1t = (bf16_t*)bp;        bp += (size_t)2 * CC * CC * 2;
  bf16_t* m_w2t = (bf16_t*)bp;        bp += (size_t)CC * 2 * CC * 2;

  bf16_t* xb = (bf16_t*)R1;      // bf16(x)
  bf16_t* xcefb = (bf16_t*)R1;   // [x_conv | ef] bf16 N x 2C
  bf16_t* qkvb = (bf16_t*)R1;    // qkv bf16 N x 1536
  bf16_t* hb = (bf16_t*)R1;      // mlp hidden bf16 N x 2C
  bf16_t* eacsr = (bf16_t*)((char*)R1 + (size_t)64 * 1024 * 1024);  // 16.8MB
  bf16_t* xwT = (bf16_t*)R2;     // (x@gcn_w)^T bf16 [512][16384]
  bf16_t* gpreb = (bf16_t*)R2;   // gate pre-act bf16 (after xwT dead)
  bf16_t* ob = (bf16_t*)R2;      // attn out bf16 (first half of R2)
  bf16_t* vt = ob + (size_t)NN * CC;  // V^T packed (second half of R2)
  bf16_t* x3b = (bf16_t*)R2;     // bf16(x3) (after ob dead)
  bf16_t* AnFull = (bf16_t*)R3;  // dense adjacency bf16 [16384][256] (8MB)
  bf16_t* oprjb = (bf16_t*)R4;   // out-proj bf16
  float* yf = R4;                // mlp2 f32 out (after oprjb dead)

  // --- edge prep ---
  init_kernel<<<1, 256, 0, stream>>>(ghist, nid_src, eacsr);
  edge_pass1<<<EE / 256, 256, 0, stream>>>(dst, ghist);
  gexscan_kernel<<<1, 64, 0, stream>>>(ghist, gstart, gcur);
  graph_scatter_kernel<<<EE / 2048, 256, 0, stream>>>(src, dst, edge_attr, gcur,
                                                      grec, ewg);
  graph_sort2_kernel<<<128, 1024, 0, stream>>>(grec, ewg, gstart, elist_src, nid_src,
                                               start_src, dstrec, start_dst, dinv);
  ea_gather_kernel<<<(EE * 2 + 255) / 256, 256, 0, stream>>>(edge_attr, elist_src,
                                                             eacsr);
  an_build_kernel<<<128, 256, 0, stream>>>(dstrec, start_dst, dinv, AnFull);

  // --- fused prep: cvt(x) + all 6 weight transposes ---
  prep_kernel<<<8192 + 2816, 256, 0, stream>>>(x, xb, gcn_w, gcn_wt, gate_w, gate_wt,
                                               in_w, in_wt, out_w, out_wt, m_w1,
                                               m_w1t, m_w2, m_w2t);

  // --- GCN conv: xwT = (x @ gcn_w)^T via flipped GEMM, then dense An GEMM ---
  gemm_bf16_kernel<0, 1><<<dim3(NN / 128, CC / 128), 512, 0, stream>>>(
      gcn_wt, xb, nullptr, xwT, CC, NN, CC);
  an_gemm_kernel<<<dim3(CC / 128, NN / 128), 512, 0, stream>>>(AnFull, xwT, gcn_b,
                                                               xcefb);
  ef_mfma_kernel<<<NN / 16, 512, 0, stream>>>(eacsr, ep_w, ep_b, nid_src, start_src,
                                              xcefb);
  dim3 gA(CC / 128, NN / 128);
  gemm_bf16_kernel<0, 1><<<gA, 512, 0, stream>>>(xcefb, gate_wt, nullptr, gpreb, NN,
                                                 CC, 2 * CC);
  ln_gate_kernel<<<NN, 128, 0, stream>>>(gpreb, gate_b, xcefb, n1_g, n1_b, x, x2b);

  // --- MHA ---
  dim3 gQ(3 * CC / 128, NN / 128);
  gemm_bf16_kernel<0, 1><<<gQ, 512, 0, stream>>>(x2b, in_wt, in_b, qkvb, NN, 3 * CC, CC);
  vt_pack_kernel<<<BB * HH, 256, 0, stream>>>(qkvb, vt);
  attn_mfma_kernel<<<BB * HH, 256, 0, stream>>>(qkvb, vt, ob);
  gemm_bf16_kernel<0, 1><<<gA, 512, 0, stream>>>(ob, out_wt, out_b, oprjb, NN, CC, CC);
  ln_addT_kernel<1, 1, 0><<<NN, 128, 0, stream>>>(x2b, oprjb, tn_g, tn_b, nullptr, x3b);

  // --- MLP ---
  dim3 gH(2 * CC / 128, NN / 128);
  gemm_bf16_kernel<1, 1><<<gH, 512, 0, stream>>>(x3b, m_w1t, m_b1, hb, NN, 2 * CC, CC);
  gemm_bf16_kernel<0, 0><<<gA, 512, 0, stream>>>(hb, m_w2t, m_b2, yf, NN, CC, 2 * CC);
  ln_addT_kernel<1, 0, 1><<<NN, 128, 0, stream>>>(x3b, yf, fn_g, fn_b, (float*)d_out,
                                                  nullptr);
}